// Round 10
// baseline (10042.326 us; speedup 1.0000x reference)
//
#include <hip/hip_runtime.h>

#define BSZ 512
#define LSEQ 128
#define HH 512
#define AA 128
#define NC 640    // H + A
#define N1 1152   // H + NC
#define KD 512

typedef short s8v __attribute__((ext_vector_type(8)));
typedef float f4v __attribute__((ext_vector_type(4)));

__device__ __forceinline__ unsigned short bf16_rne(float f) {
  unsigned int u = __float_as_uint(f);
  u += 0x7fffu + ((u >> 16) & 1u);
  return (unsigned short)(u >> 16);
}
__device__ __forceinline__ float bf16_tof(unsigned short s) {
  return __uint_as_float(((unsigned int)s) << 16);
}
__device__ __forceinline__ float fast_tanh(float x) {
  float t = __expf(2.f * x);
  return 1.f - 2.f / (t + 1.f);
}

// ---------------- prep kernels ----------------

__global__ __launch_bounds__(256) void concat_k(
    const float* __restrict__ U, const float* __restrict__ Ua1,
    const float* __restrict__ W, const float* __restrict__ Wa1,
    const float* __restrict__ bb, const float* __restrict__ ba1,
    float* __restrict__ Ucat, float* __restrict__ Wcat, float* __restrict__ bias2)
{
  int idx = blockIdx.x * 256 + threadIdx.x;
  if (idx < KD * NC) {
    int k = idx / NC, c = idx % NC;
    Ucat[idx] = (c < HH) ? U[k * HH + c] : Ua1[k * AA + (c - HH)];
    Wcat[idx] = (c < HH) ? W[k * HH + c] : Wa1[k * AA + (c - HH)];
  }
  if (idx < NC) bias2[idx] = (idx < HH) ? bb[idx] : ba1[idx - HH];
}

__global__ __launch_bounds__(NC) void comb_k(
    const float* __restrict__ Wemb, const float* __restrict__ Wcat,
    float* __restrict__ Wcomb)
{
  __shared__ float arow[KD];
  int m = blockIdx.x, n = threadIdx.x;
  for (int i = threadIdx.x; i < KD; i += NC) arow[i] = Wemb[m * HH + i];
  __syncthreads();
  float a0 = 0.f, a1 = 0.f, a2 = 0.f, a3 = 0.f;
  for (int k = 0; k < KD; k += 4) {
    a0 = fmaf(arow[k],     Wcat[(size_t)(k)     * NC + n], a0);
    a1 = fmaf(arow[k + 1], Wcat[(size_t)(k + 1) * NC + n], a1);
    a2 = fmaf(arow[k + 2], Wcat[(size_t)(k + 2) * NC + n], a2);
    a3 = fmaf(arow[k + 3], Wcat[(size_t)(k + 3) * NC + n], a3);
  }
  Wcomb[(size_t)m * NC + n] = (a0 + a1) + (a2 + a3);
}

__global__ __launch_bounds__(NC) void bcomb_k(
    const float* __restrict__ bemb, const float* __restrict__ Wcat,
    const float* __restrict__ bias2, float* __restrict__ bias1)
{
  __shared__ float be[KD];
  int n = threadIdx.x;
  for (int i = n; i < KD; i += NC) be[i] = bemb[i];
  __syncthreads();
  float acc = 0.f;
  for (int k = 0; k < KD; ++k) acc = fmaf(be[k], Wcat[(size_t)k * NC + n], acc);
  bias1[HH + n] = acc + bias2[n];
  if (n < HH) bias1[n] = bemb[n];
}

__global__ __launch_bounds__(256) void tsplit_k(
    const float* __restrict__ src, int N,
    unsigned short* __restrict__ dsth, unsigned short* __restrict__ dstl, int row_off)
{
  __shared__ float tile[32][33];
  int k0 = blockIdx.x * 32, n0 = blockIdx.y * 32;
  int tx = threadIdx.x & 31, ty = threadIdx.x >> 5;
  for (int i = ty; i < 32; i += 8) {
    int n = n0 + tx;
    tile[i][tx] = (n < N) ? src[(size_t)(k0 + i) * N + n] : 0.f;
  }
  __syncthreads();
  for (int i = ty; i < 32; i += 8) {
    int n = n0 + i;
    if (n >= N) continue;
    float v = tile[tx][i];
    unsigned short h = bf16_rne(v);
    unsigned short l = bf16_rne(v - bf16_tof(h));
    dsth[(size_t)(row_off + n) * KD + k0 + tx] = h;
    dstl[(size_t)(row_off + n) * KD + k0 + tx] = l;
  }
}

__global__ __launch_bounds__(256) void splitx_k(
    const float* __restrict__ x, unsigned short* __restrict__ xh,
    unsigned short* __restrict__ xl, int n4)
{
  int i = blockIdx.x * 256 + threadIdx.x;
  if (i >= n4) return;
  const float4 v = *(const float4*)&x[(size_t)i * 4];
  unsigned short h0 = bf16_rne(v.x), h1 = bf16_rne(v.y), h2 = bf16_rne(v.z), h3 = bf16_rne(v.w);
  unsigned short l0 = bf16_rne(v.x - bf16_tof(h0));
  unsigned short l1 = bf16_rne(v.y - bf16_tof(h1));
  unsigned short l2 = bf16_rne(v.z - bf16_tof(h2));
  unsigned short l3 = bf16_rne(v.w - bf16_tof(h3));
  *(ushort4*)&xh[(size_t)i * 4] = make_ushort4(h0, h1, h2, h3);
  *(ushort4*)&xl[(size_t)i * 4] = make_ushort4(l0, l1, l2, l3);
}

// pack UT hi/lo into col-group blocks, consumption order:
// gid = cg*8192 + nt*2048 + ks*128 + p*64 + lane  (16B units)
__global__ __launch_bounds__(256) void upack4_k(
    const unsigned short* __restrict__ UTh, const unsigned short* __restrict__ UTl,
    unsigned short* __restrict__ pk)
{
  int gid = blockIdx.x * 256 + threadIdx.x;
  if (gid >= 10 * 4 * 16 * 2 * 64) return;
  int lane = gid & 63;
  int p = (gid >> 6) & 1;
  int ks = (gid >> 7) & 15;
  int nt = (gid >> 11) & 3;
  int cg = gid >> 13;
  const unsigned short* src = p ? UTl : UTh;
  size_t soff = (size_t)(cg * 64 + nt * 16 + (lane & 15)) * KD + ks * 32 + (lane >> 4) * 8;
  *(s8v*)&pk[(size_t)gid * 8] = *(const s8v*)&src[soff];
}

// ---------------- split-bf16 3-term MFMA GEMM (unchanged) ----------------
template<int REMAP, int OMODE>
__global__ __launch_bounds__(256, 2) void gemm_k(
    const unsigned short* __restrict__ Ah, const unsigned short* __restrict__ Al,
    const unsigned short* __restrict__ BTh, const unsigned short* __restrict__ BTl,
    const float* __restrict__ bias, int NT, int c0,
    unsigned short* __restrict__ o_xeh, unsigned short* __restrict__ o_xel,
    float* __restrict__ o_xp)
{
  __shared__ __align__(16) unsigned short As_h[128][72];
  __shared__ __align__(16) unsigned short As_l[128][72];
  __shared__ __align__(16) unsigned short Bs_h[128][72];
  __shared__ __align__(16) unsigned short Bs_l[128][72];
  const int tid = threadIdx.x;
  const int lane = tid & 63, w = tid >> 6;
  const int wm = w >> 1, wn = w & 1;
  const int m0 = (blockIdx.x / NT) * 128, n0 = (blockIdx.x % NT) * 128;

  f4v acc[4][4];
#pragma unroll
  for (int i = 0; i < 4; ++i)
#pragma unroll
    for (int j = 0; j < 4; ++j) acc[i][j] = (f4v){0.f, 0.f, 0.f, 0.f};

  for (int kt = 0; kt < KD; kt += 64) {
    __syncthreads();
#pragma unroll
    for (int p = 0; p < 4; ++p) {
      int li = tid + p * 256;
      int row = li >> 3, kc = (li & 7) << 3;
      int m = m0 + row;
      int arow = REMAP ? ((m & 511) * 128 + c0 + (m >> 9)) : m;
      *(s8v*)&As_h[row][kc] = *(const s8v*)&Ah[(size_t)arow * KD + kt + kc];
      *(s8v*)&As_l[row][kc] = *(const s8v*)&Al[(size_t)arow * KD + kt + kc];
      *(s8v*)&Bs_h[row][kc] = *(const s8v*)&BTh[(size_t)(n0 + row) * KD + kt + kc];
      *(s8v*)&Bs_l[row][kc] = *(const s8v*)&BTl[(size_t)(n0 + row) * KD + kt + kc];
    }
    __syncthreads();
#pragma unroll
    for (int kk = 0; kk < 2; ++kk) {
      const int kb = kk * 32 + (lane >> 4) * 8;
      s8v ah[4], alo[4], bh[4], blo[4];
#pragma unroll
      for (int i = 0; i < 4; ++i) {
        int ra = wm * 64 + i * 16 + (lane & 15);
        int rb = wn * 64 + i * 16 + (lane & 15);
        ah[i]  = *(const s8v*)&As_h[ra][kb];
        alo[i] = *(const s8v*)&As_l[ra][kb];
        bh[i]  = *(const s8v*)&Bs_h[rb][kb];
        blo[i] = *(const s8v*)&Bs_l[rb][kb];
      }
#pragma unroll
      for (int mi = 0; mi < 4; ++mi)
#pragma unroll
        for (int ni = 0; ni < 4; ++ni) {
          acc[mi][ni] = __builtin_amdgcn_mfma_f32_16x16x32_bf16(alo[mi], bh[ni], acc[mi][ni], 0, 0, 0);
          acc[mi][ni] = __builtin_amdgcn_mfma_f32_16x16x32_bf16(ah[mi], blo[ni], acc[mi][ni], 0, 0, 0);
          acc[mi][ni] = __builtin_amdgcn_mfma_f32_16x16x32_bf16(ah[mi], bh[ni], acc[mi][ni], 0, 0, 0);
        }
    }
  }
#pragma unroll
  for (int mi = 0; mi < 4; ++mi) {
#pragma unroll
    for (int ni = 0; ni < 4; ++ni) {
      int n = n0 + wn * 64 + ni * 16 + (lane & 15);
      float bv = bias[n];
#pragma unroll
      for (int r = 0; r < 4; ++r) {
        int m = m0 + wm * 64 + mi * 16 + (lane >> 4) * 4 + r;
        float val = acc[mi][ni][r] + bv;
        if (OMODE == 1) {
          if (n < HH) {
            unsigned short hb = bf16_rne(val);
            unsigned short lb = bf16_rne(val - bf16_tof(hb));
            o_xeh[(size_t)m * KD + n] = hb;
            o_xel[(size_t)m * KD + n] = lb;
          } else {
            o_xp[(size_t)m * NC + (n - HH)] = val;
          }
        } else {
          o_xp[(size_t)m * NC + n] = val;
        }
      }
    }
  }
}

// ---------------- cooperative weight-stationary 3-layer scan ----------------
struct SLayer {
  const unsigned short* xin_h; const unsigned short* xin_l;
  const float* xp;
  const int* ain; const int* nin;
  int* aout; int* nout;
  unsigned short* hout_h; unsigned short* hout_l;
  float* dd;
  int LL, c0, FIRST, active;
};
struct SArgs { SLayer l[3]; };

// per-layer 80-block barrier; all 240 blocks co-resident (147KB LDS -> 1/CU)
__device__ __forceinline__ void gbar(int* cnt, unsigned int* gen, int n) {
  __syncthreads();
  if (threadIdx.x == 0) {
    __threadfence();   // release (agent): L2 writeback
    unsigned int g = __hip_atomic_load(gen, __ATOMIC_RELAXED, __HIP_MEMORY_SCOPE_AGENT);
    int a = __hip_atomic_fetch_add(cnt, 1, __ATOMIC_ACQ_REL, __HIP_MEMORY_SCOPE_AGENT);
    if (a == n - 1) {
      __hip_atomic_store(cnt, 0, __ATOMIC_RELAXED, __HIP_MEMORY_SCOPE_AGENT);
      __hip_atomic_fetch_add(gen, 1u, __ATOMIC_RELEASE, __HIP_MEMORY_SCOPE_AGENT);
    } else {
      while (__hip_atomic_load(gen, __ATOMIC_ACQUIRE, __HIP_MEMORY_SCOPE_AGENT) == g)
        __builtin_amdgcn_s_sleep(2);
    }
    __threadfence();   // acquire (agent): invalidate
  }
  __syncthreads();
}

// grid 240 = layer(3) x [bg(8) x cg(10)]; 256 threads (4 waves).
// cg 0..7: W-cols [cg*64,+64); cg 8..9: action cols [512+(cg-8)*64,+64).
// hP layout: [lay][par][bg][k8 64][row 64][8] shorts (planes hPh/hPl).
__global__ __launch_bounds__(256) void scan4_k(
    SArgs A, const unsigned short* __restrict__ Upk4,
    unsigned short* __restrict__ hPh, unsigned short* __restrict__ hPl,
    int* __restrict__ aTb, int* __restrict__ dTb,        // [lay][par][512]
    float* __restrict__ plog,                            // [lay][512][part2][j2]
    int* __restrict__ barc, unsigned int* __restrict__ barg,
    const float* __restrict__ Wa2, const float* __restrict__ ba2,
    const int* __restrict__ mask, int CH)
{
  const int bid = blockIdx.x;
  const int lay = bid / 80;
  const int rem = bid % 80;
  const int bg = rem / 10, cg = rem % 10;
  const SLayer La = A.l[lay];
  if (!La.active) return;    // per-layer barrier => safe to exit whole layer

  __shared__ __align__(16) unsigned short wgt[4][16][2][512];  // 128 KB
  __shared__ float tbuf[4][64][17];                            // 17.4 KB
  __shared__ float sWa2[AA * 2];
  __shared__ float sba2v[2];
  __shared__ int gw_b[64], gw_h[64], gw_x[64], gw_dp[64];

  const int tid = threadIdx.x;
  const int lane = tid & 63, w = tid >> 6;
  const int ar = lane & 15, g = lane >> 4;
  const int b0 = bg * 64;
  const int myrow0 = b0 + w * 16;

  // weights -> LDS once
  {
    const unsigned short* src = Upk4 + (size_t)cg * 65536;
    unsigned short* dst = &wgt[0][0][0][0];
#pragma unroll
    for (int i = 0; i < 32; ++i) {
      int idx = i * 256 + tid;
      *(s8v*)&dst[idx * 8] = *(const s8v*)&src[(size_t)idx * 8];
    }
  }
  if (tid < AA * 2) sWa2[tid] = Wa2[tid];
  if (tid < 2) sba2v[tid] = ba2[tid];
  __syncthreads();

  int* mycnt = barc + lay * 64;
  unsigned int* mygen = barg + lay * 64;
  unsigned short* hhb = hPh + (size_t)lay * 524288;
  unsigned short* hlb = hPl + (size_t)lay * 524288;

  for (int tl = 0; tl < CH; ++tl) {
    const int t = La.c0 + tl;
    const int pr = t & 1, pw = pr ^ 1;
    const int zero_h = (La.FIRST && tl == 0);
    const size_t xrow = (size_t)tl * BSZ;

    // ================= phase alpha: Y-slice MFMA =================
    f4v acc[4];
#pragma unroll
    for (int nt = 0; nt < 4; ++nt) acc[nt] = (f4v){0.f, 0.f, 0.f, 0.f};

    if (!zero_h) {
      const unsigned short* __restrict__ hA = hhb + (size_t)pr * 262144 + (size_t)bg * 32768;
      const unsigned short* __restrict__ lA = hlb + (size_t)pr * 262144 + (size_t)bg * 32768;
      const int rl = w * 16 + ar;
      s8v ah0 = *(const s8v*)&hA[(size_t)((0 * 4 + g) * 64 + rl) * 8];
      s8v al0 = *(const s8v*)&lA[(size_t)((0 * 4 + g) * 64 + rl) * 8];
      s8v ah1, al1;
#pragma unroll
      for (int ks = 0; ks < 16; ++ks) {
        if (ks < 15) {
          ah1 = *(const s8v*)&hA[(size_t)(((ks + 1) * 4 + g) * 64 + rl) * 8];
          al1 = *(const s8v*)&lA[(size_t)(((ks + 1) * 4 + g) * 64 + rl) * 8];
        }
#pragma unroll
        for (int nt = 0; nt < 4; ++nt) {
          s8v bh = *(const s8v*)&wgt[nt][ks][0][lane * 8];
          s8v bl = *(const s8v*)&wgt[nt][ks][1][lane * 8];
          acc[nt] = __builtin_amdgcn_mfma_f32_16x16x32_bf16(al0, bh, acc[nt], 0, 0, 0);
          acc[nt] = __builtin_amdgcn_mfma_f32_16x16x32_bf16(ah0, bl, acc[nt], 0, 0, 0);
          acc[nt] = __builtin_amdgcn_mfma_f32_16x16x32_bf16(ah0, bh, acc[nt], 0, 0, 0);
        }
        ah0 = ah1; al0 = al1;
      }
    }

    if (cg >= 8) {
      // pol + partial logits for this block's 64 action cols
      float sj[8];
#pragma unroll
      for (int v = 0; v < 8; ++v) sj[v] = 0.f;
#pragma unroll
      for (int nt = 0; nt < 4; ++nt) {
        int a = (cg - 8) * 64 + nt * 16 + ar;
        float w0 = sWa2[a * 2], w1 = sWa2[a * 2 + 1];
#pragma unroll
        for (int i = 0; i < 4; ++i) {
          int b = myrow0 + g * 4 + i;
          float xpa = La.xp[(xrow + b) * NC + HH + a];
          float pv = fmaxf(xpa + acc[nt][i], 0.f);
          sj[i * 2]     = fmaf(pv, w0, sj[i * 2]);
          sj[i * 2 + 1] = fmaf(pv, w1, sj[i * 2 + 1]);
        }
      }
#pragma unroll
      for (int v = 0; v < 8; ++v) {
        sj[v] += __shfl_xor(sj[v], 1);
        sj[v] += __shfl_xor(sj[v], 2);
        sj[v] += __shfl_xor(sj[v], 4);
        sj[v] += __shfl_xor(sj[v], 8);
      }
      if (ar == 0) {
#pragma unroll
        for (int i = 0; i < 4; ++i) {
          int b = myrow0 + g * 4 + i;
          plog[((size_t)lay * 512 + b) * 4 + (cg - 8) * 2]     = sj[i * 2];
          plog[((size_t)lay * 512 + b) * 4 + (cg - 8) * 2 + 1] = sj[i * 2 + 1];
        }
      }
    }
    gbar(mycnt, mygen, 80);

    // ================= phase beta: gates + h-update (W-blocks) =================
    if (cg < 8) {
      if (tid < 64) {
        int b = b0 + tid;
        float l0 = plog[((size_t)lay * 512 + b) * 4 + 0] + plog[((size_t)lay * 512 + b) * 4 + 2] + sba2v[0];
        float l1 = plog[((size_t)lay * 512 + b) * 4 + 1] + plog[((size_t)lay * 512 + b) * 4 + 3] + sba2v[1];
        int A0 = (La.ain && t < LSEQ - 1) ? La.ain[(t + 1) * BSZ + b] : 0;
        int DP = La.nin ? La.nin[t * BSZ + b] : mask[b * LSEQ + t];
        int mt = mask[b * LSEQ + t];
        int mn = (t < LSEQ - 1) ? mask[b * LSEQ + t + 1] : 0;
        int DT = zero_h ? 0 : dTb[(lay * 2 + pr) * 512 + b];
        int AT = zero_h ? 0 : aTb[(lay * 2 + pr) * 512 + b];
        int E = mt * (1 - mn);
        int act = (l0 >= l1) ? 1 : 0;
        if (A0 > 0) act = 1;
        if (La.LL) act = 1;
        if (E > 0) act = 0;
        int both  = (1 - A0) * DP * act * DT;
        int honly = DT * act * (A0 + (1 - A0) * (1 - DP));
        int xonly = DP * (1 - A0) * (1 - act + act * (1 - DT));
        int ndm = DP * (both + xonly + honly);
        int aout = DP ? act : AT;
        gw_b[tid] = both; gw_h[tid] = honly; gw_x[tid] = xonly; gw_dp[tid] = DP;
        if (cg == 0) {
          dTb[(lay * 2 + pw) * 512 + b] = ndm;
          aTb[(lay * 2 + pw) * 512 + b] = aout;
          if (La.aout) La.aout[t * BSZ + b] = aout;
          if (La.nout) La.nout[t * BSZ + b] = ndm;
        }
      }
#pragma unroll
      for (int nt = 0; nt < 4; ++nt)
#pragma unroll
        for (int i = 0; i < 4; ++i)
          tbuf[w][nt * 16 + ar][g * 4 + i] = acc[nt][i];
      __syncthreads();

#pragma unroll
      for (int u = 0; u < 2; ++u) {
        const int unit = u * 64 + lane;
        const int row = unit >> 3, j = unit & 7;
        const int b = myrow0 + row;
        const int dbase = cg * 64 + j * 8;
        const int BB = gw_b[w * 16 + row], HO = gw_h[w * 16 + row];
        const int XO = gw_x[w * 16 + row], DPb = gw_dp[w * 16 + row];
        float yw[8];
#pragma unroll
        for (int e = 0; e < 8; ++e) yw[e] = tbuf[w][j * 8 + e][row];
        float4 xp0 = *(const float4*)&La.xp[(xrow + b) * NC + dbase];
        float4 xp1 = *(const float4*)&La.xp[(xrow + b) * NC + dbase + 4];
        float xpv[8] = {xp0.x, xp0.y, xp0.z, xp0.w, xp1.x, xp1.y, xp1.z, xp1.w};
        const size_t hoff = (size_t)(cg * 8 + j) * 64 + (w * 16 + row);
        s8v oh_ = {0,0,0,0,0,0,0,0}, ol_ = {0,0,0,0,0,0,0,0};
        if (!zero_h) {
          oh_ = *(const s8v*)&hhb[(size_t)pr * 262144 + (size_t)bg * 32768 + hoff * 8];
          ol_ = *(const s8v*)&hlb[(size_t)pr * 262144 + (size_t)bg * 32768 + hoff * 8];
        }
        s8v xh_ = *(const s8v*)&La.xin_h[(xrow + b) * KD + dbase];
        s8v xl_ = *(const s8v*)&La.xin_l[(xrow + b) * KD + dbase];
        s8v nh, nl;
        float outv[8];
#pragma unroll
        for (int e = 0; e < 8; ++e) {
          float hold = bf16_tof((unsigned short)oh_[e]) + bf16_tof((unsigned short)ol_[e]);
          float v;
          if (BB) v = fast_tanh(xpv[e] + yw[e]);
          else if (HO) v = hold;
          else if (XO) v = bf16_tof((unsigned short)xh_[e]) + bf16_tof((unsigned short)xl_[e]);
          else v = 0.f;
          if (!DPb) v = hold;
          unsigned short hb = bf16_rne(v);
          nh[e] = (short)hb;
          nl[e] = (short)bf16_rne(v - bf16_tof(hb));
          outv[e] = v;
        }
        *(s8v*)&hhb[(size_t)pw * 262144 + (size_t)bg * 32768 + hoff * 8] = nh;
        *(s8v*)&hlb[(size_t)pw * 262144 + (size_t)bg * 32768 + hoff * 8] = nl;
        if (La.hout_h) {
          *(s8v*)&La.hout_h[(xrow + b) * KD + dbase] = nh;
          *(s8v*)&La.hout_l[(xrow + b) * KD + dbase] = nl;
        }
        if (La.dd && t == LSEQ - 1) {
          *(float4*)&La.dd[(size_t)b * KD + dbase]     = make_float4(outv[0], outv[1], outv[2], outv[3]);
          *(float4*)&La.dd[(size_t)b * KD + dbase + 4] = make_float4(outv[4], outv[5], outv[6], outv[7]);
        }
      }
    }
    gbar(mycnt, mygen, 80);
  }
}

// ---------------- host ----------------
extern "C" void kernel_launch(void* const* d_in, const int* in_sizes, int n_in,
                              void* d_out, int out_size, void* d_ws, size_t ws_size,
                              hipStream_t stream)
{
  (void)in_sizes; (void)n_in; (void)out_size;
  const float* x    = (const float*)d_in[0];
  const int*   mask = (const int*)d_in[2];
  const float* Wemb = (const float*)d_in[3];
  const float* bemb = (const float*)d_in[4];
  const float* Wm   = (const float*)d_in[5];
  const float* Um   = (const float*)d_in[6];
  const float* bm   = (const float*)d_in[7];
  const float* Wa1  = (const float*)d_in[8];
  const float* Ua1  = (const float*)d_in[9];
  const float* ba1  = (const float*)d_in[10];
  const float* Wa2  = (const float*)d_in[11];
  const float* ba2  = (const float*)d_in[12];
  float* out = (float*)d_out;

  const size_t FIXED = (size_t)172 << 20;
  const size_t PER_CH = (size_t)12 << 20;
  int CH = 4;
  {
    const int cands[3] = {16, 8, 4};
    for (int i = 0; i < 3; ++i)
      if (FIXED + (size_t)cands[i] * PER_CH <= ws_size) { CH = cands[i]; break; }
  }
  const int NCH = LSEQ / CH;

  char* p = (char*)d_ws;
  auto alloc = [&](size_t bytes) { char* r = p; p += (bytes + 255) & ~(size_t)255; return r; };

  float* Ucat  = (float*)alloc((size_t)KD * NC * 4);
  float* Wcat  = (float*)alloc((size_t)KD * NC * 4);
  float* Wcomb = (float*)alloc((size_t)KD * NC * 4);
  float* bias1 = (float*)alloc(N1 * 4);
  float* bias2 = (float*)alloc(NC * 4);
  unsigned short* BT1h = (unsigned short*)alloc((size_t)N1 * KD * 2);
  unsigned short* BT1l = (unsigned short*)alloc((size_t)N1 * KD * 2);
  unsigned short* BT2h = (unsigned short*)alloc((size_t)NC * KD * 2);
  unsigned short* BT2l = (unsigned short*)alloc((size_t)NC * KD * 2);
  unsigned short* UTh  = (unsigned short*)alloc((size_t)NC * KD * 2);
  unsigned short* UTl  = (unsigned short*)alloc((size_t)NC * KD * 2);
  unsigned short* Upk4 = (unsigned short*)alloc((size_t)10 * 65536 * 2);
  int* acts0 = (int*)alloc((size_t)LSEQ * BSZ * 4);
  int* ndms0 = (int*)alloc((size_t)LSEQ * BSZ * 4);
  int* acts1 = (int*)alloc((size_t)LSEQ * BSZ * 4);
  int* ndms1 = (int*)alloc((size_t)LSEQ * BSZ * 4);
  unsigned short* hPh = (unsigned short*)alloc((size_t)3 * 524288 * 2);
  unsigned short* hPl = (unsigned short*)alloc((size_t)3 * 524288 * 2);
  int* aTb = (int*)alloc((size_t)3 * 2 * 512 * 4);
  int* dTb = (int*)alloc((size_t)3 * 2 * 512 * 4);
  float* plog = (float*)alloc((size_t)3 * 512 * 4 * 4);
  int* barc = (int*)alloc(3 * 64 * 4);
  unsigned int* barg = (unsigned int*)alloc(3 * 64 * 4);
  const size_t XEL = (size_t)BSZ * LSEQ * KD;
  unsigned short* xph = (unsigned short*)alloc(XEL * 2);
  unsigned short* xpl = (unsigned short*)alloc(XEL * 2);
  const size_t CE = (size_t)CH * BSZ * KD;
  unsigned short* xeh = (unsigned short*)alloc(CE * 2);
  unsigned short* xel = (unsigned short*)alloc(CE * 2);
  unsigned short* h0h[3], *h0l[3], *h1h[3], *h1l[3];
  for (int i = 0; i < 3; ++i) {
    h0h[i] = (unsigned short*)alloc(CE * 2); h0l[i] = (unsigned short*)alloc(CE * 2);
    h1h[i] = (unsigned short*)alloc(CE * 2); h1l[i] = (unsigned short*)alloc(CE * 2);
  }
  float* XP0 = (float*)alloc((size_t)CH * BSZ * NC * 4);
  float* XP1 = (float*)alloc((size_t)CH * BSZ * NC * 4);
  float* XP2 = (float*)alloc((size_t)CH * BSZ * NC * 4);

  hipMemsetAsync(barc, 0, 3 * 64 * 4, stream);
  hipMemsetAsync(barg, 0, 3 * 64 * 4, stream);

  concat_k<<<(KD * NC + 255) / 256, 256, 0, stream>>>(Um, Ua1, Wm, Wa1, bm, ba1, Ucat, Wcat, bias2);
  comb_k<<<KD, NC, 0, stream>>>(Wemb, Wcat, Wcomb);
  bcomb_k<<<1, NC, 0, stream>>>(bemb, Wcat, bias2, bias1);
  tsplit_k<<<dim3(16, 16), 256, 0, stream>>>(Wemb, HH, BT1h, BT1l, 0);
  tsplit_k<<<dim3(16, 20), 256, 0, stream>>>(Wcomb, NC, BT1h, BT1l, HH);
  tsplit_k<<<dim3(16, 20), 256, 0, stream>>>(Wcat, NC, BT2h, BT2l, 0);
  tsplit_k<<<dim3(16, 20), 256, 0, stream>>>(Ucat, NC, UTh, UTl, 0);
  upack4_k<<<(10 * 8192 + 255) / 256, 256, 0, stream>>>(UTh, UTl, Upk4);
  splitx_k<<<(int)((XEL / 4 + 255) / 256), 256, 0, stream>>>(x, xph, xpl, (int)(XEL / 4));

  for (int s = 0; s < NCH + 4; ++s) {
    const int c0i = s, c1i = s - 2, c2i = s - 4;
    const bool a0 = (c0i >= 0 && c0i < NCH);
    const bool a1 = (c1i >= 0 && c1i < NCH);
    const bool a2 = (c2i >= 0 && c2i < NCH);
    const int s0 = a0 ? (c0i % 3) : 0, s1 = a1 ? (c1i % 3) : 0, s2 = a2 ? (c2i % 3) : 0;

    if (a0) gemm_k<1, 1><<<CH * 36, 256, 0, stream>>>(xph, xpl, BT1h, BT1l, bias1, 9, c0i * CH,
                                                      xeh, xel, XP0);
    if (a1) gemm_k<0, 2><<<CH * 20, 256, 0, stream>>>(h0h[s1], h0l[s1], BT2h, BT2l, bias2, 5, 0,
                                                      nullptr, nullptr, XP1);
    if (a2) gemm_k<0, 2><<<CH * 20, 256, 0, stream>>>(h1h[s2], h1l[s2], BT2h, BT2l, bias2, 5, 0,
                                                      nullptr, nullptr, XP2);

    SArgs A{};
    A.l[0] = SLayer{ xeh, xel, XP0, nullptr, nullptr, acts0, ndms0,
                     h0h[s0], h0l[s0], nullptr, 0, c0i * CH, c0i == 0, a0 ? 1 : 0 };
    A.l[1] = SLayer{ h0h[s1], h0l[s1], XP1, acts0, ndms0, acts1, ndms1,
                     h1h[s1], h1l[s1], nullptr, 0, c1i * CH, c1i == 0, a1 ? 1 : 0 };
    A.l[2] = SLayer{ h1h[s2], h1l[s2], XP2, acts1, ndms1, nullptr, nullptr,
                     nullptr, nullptr, out, 1, c2i * CH, c2i == 0, a2 ? 1 : 0 };
    scan4_k<<<240, 256, 0, stream>>>(A, Upk4, hPh, hPl, aTb, dTb, plog, barc, barg,
                                     Wa2, ba2, mask, CH);
  }
}

// Round 11
// 9099.384 us; speedup vs baseline: 1.1036x; 1.1036x over previous
//
#include <hip/hip_runtime.h>

#define BSZ 512
#define LSEQ 128
#define HH 512
#define AA 128
#define NC 640    // H + A
#define N1 1152   // H + NC
#define KD 512
#define SBR 16    // batch rows per scan block

typedef short s8v __attribute__((ext_vector_type(8)));
typedef float f4v __attribute__((ext_vector_type(4)));

__device__ __forceinline__ unsigned short bf16_rne(float f) {
  unsigned int u = __float_as_uint(f);
  u += 0x7fffu + ((u >> 16) & 1u);
  return (unsigned short)(u >> 16);
}
__device__ __forceinline__ float bf16_tof(unsigned short s) {
  return __uint_as_float(((unsigned int)s) << 16);
}
__device__ __forceinline__ float fast_tanh(float x) {
  float t = __expf(2.f * x);
  return 1.f - 2.f / (t + 1.f);
}

// ---------------- prep kernels ----------------

__global__ __launch_bounds__(256) void concat_k(
    const float* __restrict__ U, const float* __restrict__ Ua1,
    const float* __restrict__ W, const float* __restrict__ Wa1,
    const float* __restrict__ bb, const float* __restrict__ ba1,
    float* __restrict__ Ucat, float* __restrict__ Wcat, float* __restrict__ bias2)
{
  int idx = blockIdx.x * 256 + threadIdx.x;
  if (idx < KD * NC) {
    int k = idx / NC, c = idx % NC;
    Ucat[idx] = (c < HH) ? U[k * HH + c] : Ua1[k * AA + (c - HH)];
    Wcat[idx] = (c < HH) ? W[k * HH + c] : Wa1[k * AA + (c - HH)];
  }
  if (idx < NC) bias2[idx] = (idx < HH) ? bb[idx] : ba1[idx - HH];
}

__global__ __launch_bounds__(NC) void comb_k(
    const float* __restrict__ Wemb, const float* __restrict__ Wcat,
    float* __restrict__ Wcomb)
{
  __shared__ float arow[KD];
  int m = blockIdx.x, n = threadIdx.x;
  for (int i = threadIdx.x; i < KD; i += NC) arow[i] = Wemb[m * HH + i];
  __syncthreads();
  float a0 = 0.f, a1 = 0.f, a2 = 0.f, a3 = 0.f;
  for (int k = 0; k < KD; k += 4) {
    a0 = fmaf(arow[k],     Wcat[(size_t)(k)     * NC + n], a0);
    a1 = fmaf(arow[k + 1], Wcat[(size_t)(k + 1) * NC + n], a1);
    a2 = fmaf(arow[k + 2], Wcat[(size_t)(k + 2) * NC + n], a2);
    a3 = fmaf(arow[k + 3], Wcat[(size_t)(k + 3) * NC + n], a3);
  }
  Wcomb[(size_t)m * NC + n] = (a0 + a1) + (a2 + a3);
}

__global__ __launch_bounds__(NC) void bcomb_k(
    const float* __restrict__ bemb, const float* __restrict__ Wcat,
    const float* __restrict__ bias2, float* __restrict__ bias1)
{
  __shared__ float be[KD];
  int n = threadIdx.x;
  for (int i = n; i < KD; i += NC) be[i] = bemb[i];
  __syncthreads();
  float acc = 0.f;
  for (int k = 0; k < KD; ++k) acc = fmaf(be[k], Wcat[(size_t)k * NC + n], acc);
  bias1[HH + n] = acc + bias2[n];
  if (n < HH) bias1[n] = bemb[n];
}

// transpose + split f32 [KD][N] -> bf16 hi/lo [N][KD]
__global__ __launch_bounds__(256) void tsplit_k(
    const float* __restrict__ src, int N,
    unsigned short* __restrict__ dsth, unsigned short* __restrict__ dstl, int row_off)
{
  __shared__ float tile[32][33];
  int k0 = blockIdx.x * 32, n0 = blockIdx.y * 32;
  int tx = threadIdx.x & 31, ty = threadIdx.x >> 5;
  for (int i = ty; i < 32; i += 8) {
    int n = n0 + tx;
    tile[i][tx] = (n < N) ? src[(size_t)(k0 + i) * N + n] : 0.f;
  }
  __syncthreads();
  for (int i = ty; i < 32; i += 8) {
    int n = n0 + i;
    if (n >= N) continue;
    float v = tile[tx][i];
    unsigned short h = bf16_rne(v);
    unsigned short l = bf16_rne(v - bf16_tof(h));
    dsth[(size_t)(row_off + n) * KD + k0 + tx] = h;
    dstl[(size_t)(row_off + n) * KD + k0 + tx] = l;
  }
}

// split f32 -> bf16 hi/lo planes (flat)
__global__ __launch_bounds__(256) void splitx_k(
    const float* __restrict__ x, unsigned short* __restrict__ xh,
    unsigned short* __restrict__ xl, int n4)
{
  int i = blockIdx.x * 256 + threadIdx.x;
  if (i >= n4) return;
  const float4 v = *(const float4*)&x[(size_t)i * 4];
  unsigned short h0 = bf16_rne(v.x), h1 = bf16_rne(v.y), h2 = bf16_rne(v.z), h3 = bf16_rne(v.w);
  unsigned short l0 = bf16_rne(v.x - bf16_tof(h0));
  unsigned short l1 = bf16_rne(v.y - bf16_tof(h1));
  unsigned short l2 = bf16_rne(v.z - bf16_tof(h2));
  unsigned short l3 = bf16_rne(v.w - bf16_tof(h3));
  *(ushort4*)&xh[(size_t)i * 4] = make_ushort4(h0, h1, h2, h3);
  *(ushort4*)&xl[(size_t)i * 4] = make_ushort4(l0, l1, l2, l3);
}

// pack UT hi/lo into per-wave, consumption-ordered contiguous tiles
__global__ __launch_bounds__(256) void upack_k(
    const unsigned short* __restrict__ UTh, const unsigned short* __restrict__ UTl,
    unsigned short* __restrict__ pk)
{
  int gid = blockIdx.x * 256 + threadIdx.x;   // tile*128 + p*64 + lane
  if (gid >= 8 * 80 * 2 * 64) return;
  int lane = gid & 63;
  int p = (gid >> 6) & 1;
  int tile = gid >> 7;                        // w*80 + ks*5 + nt
  int w = tile / 80;
  int rem = tile - w * 80;
  int ks = rem / 5, nt = rem - ks * 5;
  const unsigned short* src = p ? UTl : UTh;
  size_t soff = (size_t)(w * 80 + nt * 16 + (lane & 15)) * KD + ks * 32 + (lane >> 4) * 8;
  *(s8v*)&pk[(size_t)gid * 8] = *(const s8v*)&src[soff];
}

// ---------------- split-bf16 3-term MFMA GEMM ----------------
template<int REMAP, int OMODE>
__global__ __launch_bounds__(256, 2) void gemm_k(
    const unsigned short* __restrict__ Ah, const unsigned short* __restrict__ Al,
    const unsigned short* __restrict__ BTh, const unsigned short* __restrict__ BTl,
    const float* __restrict__ bias, int NT, int c0,
    unsigned short* __restrict__ o_xeh, unsigned short* __restrict__ o_xel,
    float* __restrict__ o_xp)
{
  __shared__ __align__(16) unsigned short As_h[128][72];
  __shared__ __align__(16) unsigned short As_l[128][72];
  __shared__ __align__(16) unsigned short Bs_h[128][72];
  __shared__ __align__(16) unsigned short Bs_l[128][72];
  const int tid = threadIdx.x;
  const int lane = tid & 63, w = tid >> 6;
  const int wm = w >> 1, wn = w & 1;
  const int m0 = (blockIdx.x / NT) * 128, n0 = (blockIdx.x % NT) * 128;

  f4v acc[4][4];
#pragma unroll
  for (int i = 0; i < 4; ++i)
#pragma unroll
    for (int j = 0; j < 4; ++j) acc[i][j] = (f4v){0.f, 0.f, 0.f, 0.f};

  for (int kt = 0; kt < KD; kt += 64) {
    __syncthreads();
#pragma unroll
    for (int p = 0; p < 4; ++p) {
      int li = tid + p * 256;
      int row = li >> 3, kc = (li & 7) << 3;
      int m = m0 + row;
      int arow = REMAP ? ((m & 511) * 128 + c0 + (m >> 9)) : m;
      *(s8v*)&As_h[row][kc] = *(const s8v*)&Ah[(size_t)arow * KD + kt + kc];
      *(s8v*)&As_l[row][kc] = *(const s8v*)&Al[(size_t)arow * KD + kt + kc];
      *(s8v*)&Bs_h[row][kc] = *(const s8v*)&BTh[(size_t)(n0 + row) * KD + kt + kc];
      *(s8v*)&Bs_l[row][kc] = *(const s8v*)&BTl[(size_t)(n0 + row) * KD + kt + kc];
    }
    __syncthreads();
#pragma unroll
    for (int kk = 0; kk < 2; ++kk) {
      const int kb = kk * 32 + (lane >> 4) * 8;
      s8v ah[4], alo[4], bh[4], blo[4];
#pragma unroll
      for (int i = 0; i < 4; ++i) {
        int ra = wm * 64 + i * 16 + (lane & 15);
        int rb = wn * 64 + i * 16 + (lane & 15);
        ah[i]  = *(const s8v*)&As_h[ra][kb];
        alo[i] = *(const s8v*)&As_l[ra][kb];
        bh[i]  = *(const s8v*)&Bs_h[rb][kb];
        blo[i] = *(const s8v*)&Bs_l[rb][kb];
      }
#pragma unroll
      for (int mi = 0; mi < 4; ++mi)
#pragma unroll
        for (int ni = 0; ni < 4; ++ni) {
          acc[mi][ni] = __builtin_amdgcn_mfma_f32_16x16x32_bf16(alo[mi], bh[ni], acc[mi][ni], 0, 0, 0);
          acc[mi][ni] = __builtin_amdgcn_mfma_f32_16x16x32_bf16(ah[mi], blo[ni], acc[mi][ni], 0, 0, 0);
          acc[mi][ni] = __builtin_amdgcn_mfma_f32_16x16x32_bf16(ah[mi], bh[ni], acc[mi][ni], 0, 0, 0);
        }
    }
  }
#pragma unroll
  for (int mi = 0; mi < 4; ++mi) {
#pragma unroll
    for (int ni = 0; ni < 4; ++ni) {
      int n = n0 + wn * 64 + ni * 16 + (lane & 15);
      float bv = bias[n];
#pragma unroll
      for (int r = 0; r < 4; ++r) {
        int m = m0 + wm * 64 + mi * 16 + (lane >> 4) * 4 + r;
        float val = acc[mi][ni][r] + bv;
        if (OMODE == 1) {
          if (n < HH) {
            unsigned short hb = bf16_rne(val);
            unsigned short lb = bf16_rne(val - bf16_tof(hb));
            __builtin_nontemporal_store(hb, &o_xeh[(size_t)m * KD + n]);
            __builtin_nontemporal_store(lb, &o_xel[(size_t)m * KD + n]);
          } else {
            __builtin_nontemporal_store(val, &o_xp[(size_t)m * NC + (n - HH)]);
          }
        } else {
          __builtin_nontemporal_store(val, &o_xp[(size_t)m * NC + n]);
        }
      }
    }
  }
}

// ---------------- fused 3-layer MFMA scan ----------------
struct LayerArgs {
  const unsigned short* xin_h; const unsigned short* xin_l;
  const float* xp;
  const int* ain; const int* nin;
  int* aout; int* nout;
  unsigned short* hout_h; unsigned short* hout_l;
  unsigned int* hst;
  int* aT; int* dT;
  float* dd;
  int LL, c0, FIRST, active;
};
struct Args3 { LayerArgs l[3]; };

// 96 blocks x 512 threads; block b: layer = b>>5, rowblock = b&31 (16 rows).
// B staged from packed weights via global_load_lds ring + counted vmcnt.
// NT hints on all streaming traffic keep the 1.31MB shared weight set
// L2-resident; XP prefetched into regs at phase-A top (T14).
__global__ __launch_bounds__(512) void scan3_k(
    Args3 A3,
    const unsigned short* __restrict__ Upk,
    const float* __restrict__ Wa2, const float* __restrict__ ba2,
    const int* __restrict__ mask, int CH)
{
  const int lay = blockIdx.x >> 5;
  const LayerArgs La = A3.l[lay];
  if (!La.active) return;

  __shared__ __align__(16) unsigned short hh[SBR][520];
  __shared__ __align__(16) unsigned short hl[SBR][520];
  __shared__ __align__(16) unsigned short ring[8][4][2][512]; // wave x slot x plane x 1KB
  __shared__ float ya[SBR][644];
  __shared__ float pol[SBR][AA];
  __shared__ float sWa2[AA * 2];
  __shared__ float sba2[2];
  __shared__ int gB[SBR], gH[SBR], gX[SBR], gDP[SBR], sAT[SBR], sDT[SBR];

  const int tid = threadIdx.x;
  const int lane = tid & 63, w = tid >> 6;
  const int b0 = (blockIdx.x & 31) * SBR;
  const int ar = lane & 15, g = lane >> 4;
  const int cola = tid & 127, rb = tid >> 7;

  if (tid < AA * 2) sWa2[tid] = Wa2[tid];
  if (tid < 2) sba2[tid] = ba2[tid];
  if (tid < SBR) {
    sAT[tid] = La.FIRST ? 0 : La.aT[b0 + tid];
    sDT[tid] = La.FIRST ? 0 : La.dT[b0 + tid];
  }
#pragma unroll
  for (int r = 0; r < SBR; ++r) {
    unsigned int u = La.FIRST ? 0u : __builtin_nontemporal_load(&La.hst[(size_t)(b0 + r) * KD + tid]);
    hh[r][tid] = (unsigned short)(u >> 16);
    hl[r][tid] = (unsigned short)(u & 0xffff);
  }
  __syncthreads();

  // packed weight base for this wave: 80 tiles x 2KB, consumption order
  const unsigned short* __restrict__ wbase = Upk + (size_t)w * 80 * 1024 + (size_t)lane * 8;

  const int br0 = b0 + 2 * w;
  const int br1 = br0 + 1;

  auto stage = [&](int j) {   // tile j -> slot j&3; contiguous 1KB per plane
    const int s = j & 3;
    const unsigned short* gh = wbase + (size_t)j * 1024;
    const unsigned short* gl = gh + 512;
    __builtin_amdgcn_global_load_lds(
        (const __attribute__((address_space(1))) void*)gh,
        (__attribute__((address_space(3))) void*)&ring[w][s][0][0], 16, 0, 0);
    __builtin_amdgcn_global_load_lds(
        (const __attribute__((address_space(1))) void*)gl,
        (__attribute__((address_space(3))) void*)&ring[w][s][1][0], 16, 0, 0);
  };

  for (int tl = 0; tl < CH; ++tl) {
    const int t = La.c0 + tl;
    const size_t xrow = (size_t)tl * BSZ + b0;

    // ---- T14: prefetch this step's XP into regs (NT), hidden under phase A ----
    const float* __restrict__ xpb = La.xp + xrow * NC;
    float xpw[16];
#pragma unroll
    for (int r = 0; r < 16; ++r)
      xpw[r] = __builtin_nontemporal_load(&xpb[(size_t)r * NC + tid]);
    float xpa[4];
#pragma unroll
    for (int q = 0; q < 4; ++q)
      xpa[q] = __builtin_nontemporal_load(&xpb[(size_t)(q * 4 + rb) * NC + HH + cola]);

    // ---- phase A: Y = h @ Ucat; ring-staged B, counted vmcnt, carry-over ----
    f4v acc[5];
#pragma unroll
    for (int nt = 0; nt < 5; ++nt) acc[nt] = (f4v){0.f, 0.f, 0.f, 0.f};

    if (tl == 0) { stage(0); stage(1); stage(2); }

#pragma unroll
    for (int ks = 0; ks < 16; ++ks) {
      const int ko = ks * 32 + g * 8;
      s8v ah = *(const s8v*)&hh[ar][ko];
      s8v al = *(const s8v*)&hl[ar][ko];
#pragma unroll
      for (int nt = 0; nt < 5; ++nt) {
        const int j = ks * 5 + nt;
        int j3 = j + 3; if (j3 >= 80) j3 -= 80;   // wrap stages next step's 0..2
        stage(j3);
        asm volatile("s_waitcnt vmcnt(6)" ::: "memory");
        const int s = j & 3;
        s8v bh = *(const s8v*)&ring[w][s][0][lane * 8];   // own 16B: linear, conflict-free
        s8v bl = *(const s8v*)&ring[w][s][1][lane * 8];
        acc[nt] = __builtin_amdgcn_mfma_f32_16x16x32_bf16(al, bh, acc[nt], 0, 0, 0);
        acc[nt] = __builtin_amdgcn_mfma_f32_16x16x32_bf16(ah, bl, acc[nt], 0, 0, 0);
        acc[nt] = __builtin_amdgcn_mfma_f32_16x16x32_bf16(ah, bh, acc[nt], 0, 0, 0);
      }
    }
#pragma unroll
    for (int nt = 0; nt < 5; ++nt)
#pragma unroll
      for (int r = 0; r < 4; ++r)
        ya[g * 4 + r][w * 80 + nt * 16 + ar] = acc[nt][r];
    __syncthreads();

    // ---- phase B: hnew (regs) + pol (LDS) ----
    float hnew_r[16];
#pragma unroll
    for (int r = 0; r < 16; ++r) hnew_r[r] = fast_tanh(xpw[r] + ya[r][tid]);
#pragma unroll
    for (int q = 0; q < 4; ++q) {
      int r = q * 4 + rb;
      pol[r][cola] = fmaxf(xpa[q] + ya[r][HH + cola], 0.f);
    }
    __syncthreads();

    // ---- phase C+D: logits + gating (wave-local) ----
    {
      int A0 = (La.ain && t < LSEQ - 1) ? La.ain[(t + 1) * BSZ + br0] : 0;
      int A1 = (La.ain && t < LSEQ - 1) ? La.ain[(t + 1) * BSZ + br1] : 0;
      int DP0 = La.nin ? La.nin[t * BSZ + br0] : mask[br0 * LSEQ + t];
      int DP1 = La.nin ? La.nin[t * BSZ + br1] : mask[br1 * LSEQ + t];
      int mt0 = mask[br0 * LSEQ + t];
      int mt1 = mask[br1 * LSEQ + t];
      int mn0 = (t < LSEQ - 1) ? mask[br0 * LSEQ + t + 1] : 0;
      int mn1 = (t < LSEQ - 1) ? mask[br1 * LSEQ + t + 1] : 0;

      const int g16 = lane >> 4, li = lane & 15;
      const int rr = 2 * w + (g16 >> 1), j = g16 & 1;
      float p = 0.f;
#pragma unroll
      for (int i = 0; i < 8; ++i)
        p = fmaf(pol[rr][li + 16 * i], sWa2[(li + 16 * i) * 2 + j], p);
      p += __shfl_xor(p, 1); p += __shfl_xor(p, 2);
      p += __shfl_xor(p, 4); p += __shfl_xor(p, 8);
      float l00 = __shfl(p, 0)  + sba2[0];
      float l01 = __shfl(p, 16) + sba2[1];
      float l10 = __shfl(p, 32) + sba2[0];
      float l11 = __shfl(p, 48) + sba2[1];
      int E0 = mt0 * (1 - mn0), E1 = mt1 * (1 - mn1);
      int act0 = (l00 >= l01) ? 1 : 0;
      if (A0 > 0) act0 = 1;
      if (La.LL) act0 = 1;
      if (E0 > 0) act0 = 0;
      int act1 = (l10 >= l11) ? 1 : 0;
      if (A1 > 0) act1 = 1;
      if (La.LL) act1 = 1;
      if (E1 > 0) act1 = 0;
      int DT0 = sDT[2 * w], DT1 = sDT[2 * w + 1];
      int both0  = (1 - A0) * DP0 * act0 * DT0;
      int honly0 = DT0 * act0 * (A0 + (1 - A0) * (1 - DP0));
      int xonly0 = DP0 * (1 - A0) * (1 - act0 + act0 * (1 - DT0));
      int ndm0 = DP0 * (both0 + xonly0 + honly0);
      int aout0 = DP0 ? act0 : sAT[2 * w];
      int both1  = (1 - A1) * DP1 * act1 * DT1;
      int honly1 = DT1 * act1 * (A1 + (1 - A1) * (1 - DP1));
      int xonly1 = DP1 * (1 - A1) * (1 - act1 + act1 * (1 - DT1));
      int ndm1 = DP1 * (both1 + xonly1 + honly1);
      int aout1 = DP1 ? act1 : sAT[2 * w + 1];
      if (lane == 0) {
        gB[2 * w] = both0; gH[2 * w] = honly0; gX[2 * w] = xonly0; gDP[2 * w] = DP0;
        sAT[2 * w] = aout0; sDT[2 * w] = ndm0;
        gB[2 * w + 1] = both1; gH[2 * w + 1] = honly1; gX[2 * w + 1] = xonly1; gDP[2 * w + 1] = DP1;
        sAT[2 * w + 1] = aout1; sDT[2 * w + 1] = ndm1;
        if (La.aout) { La.aout[t * BSZ + br0] = aout0; La.aout[t * BSZ + br1] = aout1; }
        if (La.nout) { La.nout[t * BSZ + br0] = ndm0; La.nout[t * BSZ + br1] = ndm1; }
      }
    }
    __syncthreads();

    // ---- phase E: h update + outputs (all streaming NT) ----
#pragma unroll
    for (int r = 0; r < 16; ++r) {
      float vold = bf16_tof(hh[r][tid]) + bf16_tof(hl[r][tid]);
      float v;
      if (gB[r]) v = hnew_r[r];
      else if (gH[r]) v = vold;
      else if (gX[r]) {
        unsigned short xh_ = __builtin_nontemporal_load(&La.xin_h[(xrow + r) * KD + tid]);
        unsigned short xl_ = __builtin_nontemporal_load(&La.xin_l[(xrow + r) * KD + tid]);
        v = bf16_tof(xh_) + bf16_tof(xl_);
      } else v = 0.f;
      if (!gDP[r]) v = vold;
      unsigned short hi = bf16_rne(v);
      unsigned short lo = bf16_rne(v - bf16_tof(hi));
      hh[r][tid] = hi; hl[r][tid] = lo;
      if (La.hout_h) {
        __builtin_nontemporal_store(hi, &La.hout_h[(xrow + r) * KD + tid]);
        __builtin_nontemporal_store(lo, &La.hout_l[(xrow + r) * KD + tid]);
      }
      if (La.dd && t == LSEQ - 1)
        __builtin_nontemporal_store(v, &La.dd[(size_t)(b0 + r) * KD + tid]);
    }
    __syncthreads();
  }

#pragma unroll
  for (int r = 0; r < SBR; ++r)
    __builtin_nontemporal_store(((unsigned int)hh[r][tid] << 16) | hl[r][tid],
                                &La.hst[(size_t)(b0 + r) * KD + tid]);
  if (tid < SBR) { La.aT[b0 + tid] = sAT[tid]; La.dT[b0 + tid] = sDT[tid]; }
}

// ---------------- host ----------------
extern "C" void kernel_launch(void* const* d_in, const int* in_sizes, int n_in,
                              void* d_out, int out_size, void* d_ws, size_t ws_size,
                              hipStream_t stream)
{
  (void)in_sizes; (void)n_in; (void)out_size;
  const float* x    = (const float*)d_in[0];
  const int*   mask = (const int*)d_in[2];
  const float* Wemb = (const float*)d_in[3];
  const float* bemb = (const float*)d_in[4];
  const float* Wm   = (const float*)d_in[5];
  const float* Um   = (const float*)d_in[6];
  const float* bm   = (const float*)d_in[7];
  const float* Wa1  = (const float*)d_in[8];
  const float* Ua1  = (const float*)d_in[9];
  const float* ba1  = (const float*)d_in[10];
  const float* Wa2  = (const float*)d_in[11];
  const float* ba2  = (const float*)d_in[12];
  float* out = (float*)d_out;

  const size_t FIXED = (size_t)162 << 20;
  const size_t PER_CH = (size_t)12 << 20;
  int CH = 4;
  {
    const int cands[3] = {16, 8, 4};
    for (int i = 0; i < 3; ++i)
      if (FIXED + (size_t)cands[i] * PER_CH <= ws_size) { CH = cands[i]; break; }
  }
  const int NCH = LSEQ / CH;

  char* p = (char*)d_ws;
  auto alloc = [&](size_t bytes) { char* r = p; p += (bytes + 255) & ~(size_t)255; return r; };

  float* Ucat  = (float*)alloc((size_t)KD * NC * 4);
  float* Wcat  = (float*)alloc((size_t)KD * NC * 4);
  float* Wcomb = (float*)alloc((size_t)KD * NC * 4);
  float* bias1 = (float*)alloc(N1 * 4);
  float* bias2 = (float*)alloc(NC * 4);
  unsigned short* BT1h = (unsigned short*)alloc((size_t)N1 * KD * 2);
  unsigned short* BT1l = (unsigned short*)alloc((size_t)N1 * KD * 2);
  unsigned short* BT2h = (unsigned short*)alloc((size_t)NC * KD * 2);
  unsigned short* BT2l = (unsigned short*)alloc((size_t)NC * KD * 2);
  unsigned short* UTh  = (unsigned short*)alloc((size_t)NC * KD * 2);
  unsigned short* UTl  = (unsigned short*)alloc((size_t)NC * KD * 2);
  unsigned short* Upk  = (unsigned short*)alloc((size_t)8 * 80 * 1024 * 2);
  int* acts0 = (int*)alloc((size_t)LSEQ * BSZ * 4);
  int* ndms0 = (int*)alloc((size_t)LSEQ * BSZ * 4);
  int* acts1 = (int*)alloc((size_t)LSEQ * BSZ * 4);
  int* ndms1 = (int*)alloc((size_t)LSEQ * BSZ * 4);
  unsigned int* hst0 = (unsigned int*)alloc((size_t)BSZ * KD * 4);
  unsigned int* hst1 = (unsigned int*)alloc((size_t)BSZ * KD * 4);
  unsigned int* hst2 = (unsigned int*)alloc((size_t)BSZ * KD * 4);
  int* aT0 = (int*)alloc(BSZ * 4); int* dT0 = (int*)alloc(BSZ * 4);
  int* aT1 = (int*)alloc(BSZ * 4); int* dT1 = (int*)alloc(BSZ * 4);
  int* aT2 = (int*)alloc(BSZ * 4); int* dT2 = (int*)alloc(BSZ * 4);
  const size_t XEL = (size_t)BSZ * LSEQ * KD;
  unsigned short* xph = (unsigned short*)alloc(XEL * 2);
  unsigned short* xpl = (unsigned short*)alloc(XEL * 2);
  const size_t CE = (size_t)CH * BSZ * KD;
  unsigned short* xeh = (unsigned short*)alloc(CE * 2);
  unsigned short* xel = (unsigned short*)alloc(CE * 2);
  unsigned short* h0h[3], *h0l[3], *h1h[3], *h1l[3];
  for (int i = 0; i < 3; ++i) {
    h0h[i] = (unsigned short*)alloc(CE * 2); h0l[i] = (unsigned short*)alloc(CE * 2);
    h1h[i] = (unsigned short*)alloc(CE * 2); h1l[i] = (unsigned short*)alloc(CE * 2);
  }
  float* XP0 = (float*)alloc((size_t)CH * BSZ * NC * 4);
  float* XP1 = (float*)alloc((size_t)CH * BSZ * NC * 4);
  float* XP2 = (float*)alloc((size_t)CH * BSZ * NC * 4);

  concat_k<<<(KD * NC + 255) / 256, 256, 0, stream>>>(Um, Ua1, Wm, Wa1, bm, ba1, Ucat, Wcat, bias2);
  comb_k<<<KD, NC, 0, stream>>>(Wemb, Wcat, Wcomb);
  bcomb_k<<<1, NC, 0, stream>>>(bemb, Wcat, bias2, bias1);
  tsplit_k<<<dim3(16, 16), 256, 0, stream>>>(Wemb, HH, BT1h, BT1l, 0);
  tsplit_k<<<dim3(16, 20), 256, 0, stream>>>(Wcomb, NC, BT1h, BT1l, HH);
  tsplit_k<<<dim3(16, 20), 256, 0, stream>>>(Wcat, NC, BT2h, BT2l, 0);
  tsplit_k<<<dim3(16, 20), 256, 0, stream>>>(Ucat, NC, UTh, UTl, 0);
  upack_k<<<(8 * 80 * 2 * 64 + 255) / 256, 256, 0, stream>>>(UTh, UTl, Upk);
  splitx_k<<<(int)((XEL / 4 + 255) / 256), 256, 0, stream>>>(x, xph, xpl, (int)(XEL / 4));

  for (int s = 0; s < NCH + 4; ++s) {
    const int c0i = s, c1i = s - 2, c2i = s - 4;
    const bool a0 = (c0i >= 0 && c0i < NCH);
    const bool a1 = (c1i >= 0 && c1i < NCH);
    const bool a2 = (c2i >= 0 && c2i < NCH);
    const int s0 = a0 ? (c0i % 3) : 0, s1 = a1 ? (c1i % 3) : 0, s2 = a2 ? (c2i % 3) : 0;

    if (a0) gemm_k<1, 1><<<CH * 36, 256, 0, stream>>>(xph, xpl, BT1h, BT1l, bias1, 9, c0i * CH,
                                                      xeh, xel, XP0);
    if (a1) gemm_k<0, 2><<<CH * 20, 256, 0, stream>>>(h0h[s1], h0l[s1], BT2h, BT2l, bias2, 5, 0,
                                                      nullptr, nullptr, XP1);
    if (a2) gemm_k<0, 2><<<CH * 20, 256, 0, stream>>>(h1h[s2], h1l[s2], BT2h, BT2l, bias2, 5, 0,
                                                      nullptr, nullptr, XP2);

    Args3 A3{};
    A3.l[0] = LayerArgs{ xeh, xel, XP0, nullptr, nullptr, acts0, ndms0,
                         h0h[s0], h0l[s0], hst0, aT0, dT0, nullptr,
                         0, c0i * CH, c0i == 0, a0 ? 1 : 0 };
    A3.l[1] = LayerArgs{ h0h[s1], h0l[s1], XP1, acts0, ndms0, acts1, ndms1,
                         h1h[s1], h1l[s1], hst1, aT1, dT1, nullptr,
                         0, c1i * CH, c1i == 0, a1 ? 1 : 0 };
    A3.l[2] = LayerArgs{ h1h[s2], h1l[s2], XP2, acts1, ndms1, nullptr, nullptr,
                         nullptr, nullptr, hst2, aT2, dT2, out,
                         1, c2i * CH, c2i == 0, a2 ? 1 : 0 };
    scan3_k<<<96, 512, 0, stream>>>(A3, Upk, Wa2, ba2, mask, CH);
  }
}

// Round 12
// 5885.796 us; speedup vs baseline: 1.7062x; 1.5460x over previous
//
#include <hip/hip_runtime.h>

#define BSZ 512
#define LSEQ 128
#define HH 512
#define AA 128
#define NC 640    // H + A
#define N1 1152   // H + NC
#define KD 512
#define SBR 16    // batch rows per scan block

typedef short s8v __attribute__((ext_vector_type(8)));
typedef float f4v __attribute__((ext_vector_type(4)));

__device__ __forceinline__ unsigned short bf16_rne(float f) {
  unsigned int u = __float_as_uint(f);
  u += 0x7fffu + ((u >> 16) & 1u);
  return (unsigned short)(u >> 16);
}
__device__ __forceinline__ float bf16_tof(unsigned short s) {
  return __uint_as_float(((unsigned int)s) << 16);
}
__device__ __forceinline__ float fast_tanh(float x) {
  float t = __expf(2.f * x);
  return 1.f - 2.f / (t + 1.f);
}

// ---------------- prep kernels ----------------

__global__ __launch_bounds__(256) void concat_k(
    const float* __restrict__ U, const float* __restrict__ Ua1,
    const float* __restrict__ W, const float* __restrict__ Wa1,
    const float* __restrict__ bb, const float* __restrict__ ba1,
    float* __restrict__ Ucat, float* __restrict__ Wcat, float* __restrict__ bias2)
{
  int idx = blockIdx.x * 256 + threadIdx.x;
  if (idx < KD * NC) {
    int k = idx / NC, c = idx % NC;
    Ucat[idx] = (c < HH) ? U[k * HH + c] : Ua1[k * AA + (c - HH)];
    Wcat[idx] = (c < HH) ? W[k * HH + c] : Wa1[k * AA + (c - HH)];
  }
  if (idx < NC) bias2[idx] = (idx < HH) ? bb[idx] : ba1[idx - HH];
}

__global__ __launch_bounds__(NC) void comb_k(
    const float* __restrict__ Wemb, const float* __restrict__ Wcat,
    float* __restrict__ Wcomb)
{
  __shared__ float arow[KD];
  int m = blockIdx.x, n = threadIdx.x;
  for (int i = threadIdx.x; i < KD; i += NC) arow[i] = Wemb[m * HH + i];
  __syncthreads();
  float a0 = 0.f, a1 = 0.f, a2 = 0.f, a3 = 0.f;
  for (int k = 0; k < KD; k += 4) {
    a0 = fmaf(arow[k],     Wcat[(size_t)(k)     * NC + n], a0);
    a1 = fmaf(arow[k + 1], Wcat[(size_t)(k + 1) * NC + n], a1);
    a2 = fmaf(arow[k + 2], Wcat[(size_t)(k + 2) * NC + n], a2);
    a3 = fmaf(arow[k + 3], Wcat[(size_t)(k + 3) * NC + n], a3);
  }
  Wcomb[(size_t)m * NC + n] = (a0 + a1) + (a2 + a3);
}

__global__ __launch_bounds__(NC) void bcomb_k(
    const float* __restrict__ bemb, const float* __restrict__ Wcat,
    const float* __restrict__ bias2, float* __restrict__ bias1)
{
  __shared__ float be[KD];
  int n = threadIdx.x;
  for (int i = n; i < KD; i += NC) be[i] = bemb[i];
  __syncthreads();
  float acc = 0.f;
  for (int k = 0; k < KD; ++k) acc = fmaf(be[k], Wcat[(size_t)k * NC + n], acc);
  bias1[HH + n] = acc + bias2[n];
  if (n < HH) bias1[n] = bemb[n];
}

// transpose + split f32 [KD][N] -> bf16 hi/lo [N][KD]
__global__ __launch_bounds__(256) void tsplit_k(
    const float* __restrict__ src, int N,
    unsigned short* __restrict__ dsth, unsigned short* __restrict__ dstl, int row_off)
{
  __shared__ float tile[32][33];
  int k0 = blockIdx.x * 32, n0 = blockIdx.y * 32;
  int tx = threadIdx.x & 31, ty = threadIdx.x >> 5;
  for (int i = ty; i < 32; i += 8) {
    int n = n0 + tx;
    tile[i][tx] = (n < N) ? src[(size_t)(k0 + i) * N + n] : 0.f;
  }
  __syncthreads();
  for (int i = ty; i < 32; i += 8) {
    int n = n0 + i;
    if (n >= N) continue;
    float v = tile[tx][i];
    unsigned short h = bf16_rne(v);
    unsigned short l = bf16_rne(v - bf16_tof(h));
    dsth[(size_t)(row_off + n) * KD + k0 + tx] = h;
    dstl[(size_t)(row_off + n) * KD + k0 + tx] = l;
  }
}

// split f32 -> bf16 hi/lo planes (flat)
__global__ __launch_bounds__(256) void splitx_k(
    const float* __restrict__ x, unsigned short* __restrict__ xh,
    unsigned short* __restrict__ xl, int n4)
{
  int i = blockIdx.x * 256 + threadIdx.x;
  if (i >= n4) return;
  const float4 v = *(const float4*)&x[(size_t)i * 4];
  unsigned short h0 = bf16_rne(v.x), h1 = bf16_rne(v.y), h2 = bf16_rne(v.z), h3 = bf16_rne(v.w);
  unsigned short l0 = bf16_rne(v.x - bf16_tof(h0));
  unsigned short l1 = bf16_rne(v.y - bf16_tof(h1));
  unsigned short l2 = bf16_rne(v.z - bf16_tof(h2));
  unsigned short l3 = bf16_rne(v.w - bf16_tof(h3));
  *(ushort4*)&xh[(size_t)i * 4] = make_ushort4(h0, h1, h2, h3);
  *(ushort4*)&xl[(size_t)i * 4] = make_ushort4(l0, l1, l2, l3);
}

// pack UT hi/lo into per-wave, consumption-ordered contiguous tiles
__global__ __launch_bounds__(256) void upack_k(
    const unsigned short* __restrict__ UTh, const unsigned short* __restrict__ UTl,
    unsigned short* __restrict__ pk)
{
  int gid = blockIdx.x * 256 + threadIdx.x;   // tile*128 + p*64 + lane
  if (gid >= 8 * 80 * 2 * 64) return;
  int lane = gid & 63;
  int p = (gid >> 6) & 1;
  int tile = gid >> 7;                        // w*80 + ks*5 + nt
  int w = tile / 80;
  int rem = tile - w * 80;
  int ks = rem / 5, nt = rem - ks * 5;
  const unsigned short* src = p ? UTl : UTh;
  size_t soff = (size_t)(w * 80 + nt * 16 + (lane & 15)) * KD + ks * 32 + (lane >> 4) * 8;
  *(s8v*)&pk[(size_t)gid * 8] = *(const s8v*)&src[soff];
}

// ---------------- split-bf16 3-term MFMA GEMM ----------------
template<int REMAP, int OMODE>
__global__ __launch_bounds__(256, 2) void gemm_k(
    const unsigned short* __restrict__ Ah, const unsigned short* __restrict__ Al,
    const unsigned short* __restrict__ BTh, const unsigned short* __restrict__ BTl,
    const float* __restrict__ bias, int NT, int c0,
    unsigned short* __restrict__ o_xeh, unsigned short* __restrict__ o_xel,
    float* __restrict__ o_xp)
{
  __shared__ __align__(16) unsigned short As_h[128][72];
  __shared__ __align__(16) unsigned short As_l[128][72];
  __shared__ __align__(16) unsigned short Bs_h[128][72];
  __shared__ __align__(16) unsigned short Bs_l[128][72];
  const int tid = threadIdx.x;
  const int lane = tid & 63, w = tid >> 6;
  const int wm = w >> 1, wn = w & 1;
  const int m0 = (blockIdx.x / NT) * 128, n0 = (blockIdx.x % NT) * 128;

  f4v acc[4][4];
#pragma unroll
  for (int i = 0; i < 4; ++i)
#pragma unroll
    for (int j = 0; j < 4; ++j) acc[i][j] = (f4v){0.f, 0.f, 0.f, 0.f};

  for (int kt = 0; kt < KD; kt += 64) {
    __syncthreads();
#pragma unroll
    for (int p = 0; p < 4; ++p) {
      int li = tid + p * 256;
      int row = li >> 3, kc = (li & 7) << 3;
      int m = m0 + row;
      int arow = REMAP ? ((m & 511) * 128 + c0 + (m >> 9)) : m;
      *(s8v*)&As_h[row][kc] = *(const s8v*)&Ah[(size_t)arow * KD + kt + kc];
      *(s8v*)&As_l[row][kc] = *(const s8v*)&Al[(size_t)arow * KD + kt + kc];
      *(s8v*)&Bs_h[row][kc] = *(const s8v*)&BTh[(size_t)(n0 + row) * KD + kt + kc];
      *(s8v*)&Bs_l[row][kc] = *(const s8v*)&BTl[(size_t)(n0 + row) * KD + kt + kc];
    }
    __syncthreads();
#pragma unroll
    for (int kk = 0; kk < 2; ++kk) {
      const int kb = kk * 32 + (lane >> 4) * 8;
      s8v ah[4], alo[4], bh[4], blo[4];
#pragma unroll
      for (int i = 0; i < 4; ++i) {
        int ra = wm * 64 + i * 16 + (lane & 15);
        int rb = wn * 64 + i * 16 + (lane & 15);
        ah[i]  = *(const s8v*)&As_h[ra][kb];
        alo[i] = *(const s8v*)&As_l[ra][kb];
        bh[i]  = *(const s8v*)&Bs_h[rb][kb];
        blo[i] = *(const s8v*)&Bs_l[rb][kb];
      }
#pragma unroll
      for (int mi = 0; mi < 4; ++mi)
#pragma unroll
        for (int ni = 0; ni < 4; ++ni) {
          acc[mi][ni] = __builtin_amdgcn_mfma_f32_16x16x32_bf16(alo[mi], bh[ni], acc[mi][ni], 0, 0, 0);
          acc[mi][ni] = __builtin_amdgcn_mfma_f32_16x16x32_bf16(ah[mi], blo[ni], acc[mi][ni], 0, 0, 0);
          acc[mi][ni] = __builtin_amdgcn_mfma_f32_16x16x32_bf16(ah[mi], bh[ni], acc[mi][ni], 0, 0, 0);
        }
    }
  }
#pragma unroll
  for (int mi = 0; mi < 4; ++mi) {
#pragma unroll
    for (int ni = 0; ni < 4; ++ni) {
      int n = n0 + wn * 64 + ni * 16 + (lane & 15);
      float bv = bias[n];
#pragma unroll
      for (int r = 0; r < 4; ++r) {
        int m = m0 + wm * 64 + mi * 16 + (lane >> 4) * 4 + r;
        float val = acc[mi][ni][r] + bv;
        if (OMODE == 1) {
          if (n < HH) {
            unsigned short hb = bf16_rne(val);
            unsigned short lb = bf16_rne(val - bf16_tof(hb));
            __builtin_nontemporal_store(hb, &o_xeh[(size_t)m * KD + n]);
            __builtin_nontemporal_store(lb, &o_xel[(size_t)m * KD + n]);
          } else {
            __builtin_nontemporal_store(val, &o_xp[(size_t)m * NC + (n - HH)]);
          }
        } else {
          __builtin_nontemporal_store(val, &o_xp[(size_t)m * NC + n]);
        }
      }
    }
  }
}

// ---------------- fused 3-layer MFMA scan ----------------
struct LayerArgs {
  const unsigned short* xin_h; const unsigned short* xin_l;
  const float* xp;
  const int* ain; const int* nin;
  int* aout; int* nout;
  unsigned short* hout_h; unsigned short* hout_l;
  unsigned int* hst;
  int* aT; int* dT;
  float* dd;
  int LL, c0, FIRST, active;
};
struct Args3 { LayerArgs l[3]; };

// 96 blocks x 512 threads; block b: layer = b>>5, rowblock = b&31 (16 rows).
// Phase A: 7-slot LDS ring (depth-6 pipeline, vmcnt(12)); Y stays in regs
// (no ya/pol LDS); producer-ownership phases B/E1; linear E2 for xin/hout.
__global__ __launch_bounds__(512) void scan3_k(
    Args3 A3,
    const unsigned short* __restrict__ Upk,
    const float* __restrict__ Wa2, const float* __restrict__ ba2,
    const int* __restrict__ mask, int CH)
{
  const int lay = blockIdx.x >> 5;
  const LayerArgs La = A3.l[lay];
  if (!La.active) return;

  __shared__ __align__(16) unsigned short hh[SBR][520];
  __shared__ __align__(16) unsigned short hl[SBR][520];
  __shared__ __align__(16) unsigned short ring[8][7][2][512]; // 112 KB
  __shared__ float lgp[2][SBR][2];
  __shared__ float sWa2[AA * 2];
  __shared__ float sba2[2];
  __shared__ int gB[SBR], gH[SBR], gX[SBR], gDP[SBR], sAT[SBR], sDT[SBR];

  const int tid = threadIdx.x;
  const int lane = tid & 63, w = tid >> 6;
  const int b0 = (blockIdx.x & 31) * SBR;
  const int ar = lane & 15, g = lane >> 4;

  if (tid < AA * 2) sWa2[tid] = Wa2[tid];
  if (tid < 2) sba2[tid] = ba2[tid];
  if (tid < SBR) {
    sAT[tid] = La.FIRST ? 0 : La.aT[b0 + tid];
    sDT[tid] = La.FIRST ? 0 : La.dT[b0 + tid];
  }
#pragma unroll
  for (int r = 0; r < SBR; ++r) {
    unsigned int u = La.FIRST ? 0u : __builtin_nontemporal_load(&La.hst[(size_t)(b0 + r) * KD + tid]);
    hh[r][tid] = (unsigned short)(u >> 16);
    hl[r][tid] = (unsigned short)(u & 0xffff);
  }
  __syncthreads();

  const unsigned short* __restrict__ wbase = Upk + (size_t)w * 80 * 1024 + (size_t)lane * 8;

  auto stage = [&](int atile, int slot) {
    const unsigned short* gh = wbase + (size_t)atile * 1024;
    __builtin_amdgcn_global_load_lds(
        (const __attribute__((address_space(1))) void*)gh,
        (__attribute__((address_space(3))) void*)&ring[w][slot][0][0], 16, 0, 0);
    __builtin_amdgcn_global_load_lds(
        (const __attribute__((address_space(1))) void*)(gh + 512),
        (__attribute__((address_space(3))) void*)&ring[w][slot][1][0], 16, 0, 0);
  };

  // ring state: consume slot cs (tile J), produce slot ps = (J+6)%7, addr wt = (J+6)%80
  int wt = 6, ps = 6, cs = 0;
#pragma unroll
  for (int j = 0; j < 6; ++j) stage(j, j);

  for (int tl = 0; tl < CH; ++tl) {
    const int t = La.c0 + tl;
    const size_t xrow = (size_t)tl * BSZ + b0;

    // gate inputs (tid<16), hidden under phase A
    int pA0 = 0, pDP = 0, pmt = 0, pmn = 0;
    if (tid < SBR) {
      int b = b0 + tid;
      pA0 = (La.ain && t < LSEQ - 1) ? La.ain[(t + 1) * BSZ + b] : 0;
      pDP = La.nin ? La.nin[t * BSZ + b] : mask[b * LSEQ + t];
      pmt = mask[b * LSEQ + t];
      pmn = (t < LSEQ - 1) ? mask[b * LSEQ + t + 1] : 0;
    }

    // ---- phase A: Y = h @ Ucat (Y stays in regs) ----
    f4v acc[5];
#pragma unroll
    for (int nt = 0; nt < 5; ++nt) acc[nt] = (f4v){0.f, 0.f, 0.f, 0.f};

    for (int ks = 0; ks < 16; ++ks) {
      const int ko = ks * 32 + g * 8;
      s8v ah = *(const s8v*)&hh[ar][ko];
      s8v al = *(const s8v*)&hl[ar][ko];
#pragma unroll
      for (int nt = 0; nt < 5; ++nt) {
        stage(wt, ps);
        wt = (wt == 79) ? 0 : wt + 1;
        ps = (ps == 6) ? 0 : ps + 1;
        asm volatile("s_waitcnt vmcnt(12)" ::: "memory");
        s8v bh = *(const s8v*)&ring[w][cs][0][lane * 8];
        s8v bl = *(const s8v*)&ring[w][cs][1][lane * 8];
        cs = (cs == 6) ? 0 : cs + 1;
        acc[nt] = __builtin_amdgcn_mfma_f32_16x16x32_bf16(al, bh, acc[nt], 0, 0, 0);
        acc[nt] = __builtin_amdgcn_mfma_f32_16x16x32_bf16(ah, bl, acc[nt], 0, 0, 0);
        acc[nt] = __builtin_amdgcn_mfma_f32_16x16x32_bf16(ah, bh, acc[nt], 0, 0, 0);
      }
    }

    // ---- phase B: producer-ownership tanh / pol+partial-logits ----
    float hnw[5][4];
    float sj[8];
#pragma unroll
    for (int v = 0; v < 8; ++v) sj[v] = 0.f;
#pragma unroll
    for (int nt = 0; nt < 5; ++nt) {
      const int c = w * 80 + nt * 16 + ar;
      if (c < HH) {
#pragma unroll
        for (int i = 0; i < 4; ++i) {
          float xv = __builtin_nontemporal_load(&La.xp[(xrow + g * 4 + i) * NC + c]);
          hnw[nt][i] = fast_tanh(xv + acc[nt][i]);
        }
      } else {
        const int a = c - HH;
        const float w0 = sWa2[a * 2], w1 = sWa2[a * 2 + 1];
#pragma unroll
        for (int i = 0; i < 4; ++i) {
          float xv = __builtin_nontemporal_load(&La.xp[(xrow + g * 4 + i) * NC + c]);
          float pv = fmaxf(xv + acc[nt][i], 0.f);
          sj[i * 2]     = fmaf(pv, w0, sj[i * 2]);
          sj[i * 2 + 1] = fmaf(pv, w1, sj[i * 2 + 1]);
        }
      }
    }
    if (w >= 6) {
#pragma unroll
      for (int v = 0; v < 8; ++v) {
        sj[v] += __shfl_xor(sj[v], 1);
        sj[v] += __shfl_xor(sj[v], 2);
        sj[v] += __shfl_xor(sj[v], 4);
        sj[v] += __shfl_xor(sj[v], 8);
      }
      if (ar == 0) {
#pragma unroll
        for (int i = 0; i < 4; ++i) {
          lgp[w - 6][g * 4 + i][0] = sj[i * 2];
          lgp[w - 6][g * 4 + i][1] = sj[i * 2 + 1];
        }
      }
    }
    __syncthreads();   // b1: lgp visible

    // ---- gates (tid<16) ----
    if (tid < SBR) {
      float l0 = lgp[0][tid][0] + lgp[1][tid][0] + sba2[0];
      float l1 = lgp[0][tid][1] + lgp[1][tid][1] + sba2[1];
      int E = pmt * (1 - pmn);
      int act = (l0 >= l1) ? 1 : 0;
      if (pA0 > 0) act = 1;
      if (La.LL) act = 1;
      if (E > 0) act = 0;
      int DT = sDT[tid];
      int both  = (1 - pA0) * pDP * act * DT;
      int honly = DT * act * (pA0 + (1 - pA0) * (1 - pDP));
      int xonly = pDP * (1 - pA0) * (1 - act + act * (1 - DT));
      int ndm = pDP * (both + xonly + honly);
      int aout = pDP ? act : sAT[tid];
      gB[tid] = both; gH[tid] = honly; gX[tid] = xonly; gDP[tid] = pDP;
      sAT[tid] = aout; sDT[tid] = ndm;
      if (La.aout) La.aout[t * BSZ + b0 + tid] = aout;
      if (La.nout) La.nout[t * BSZ + b0 + tid] = ndm;
    }
    __syncthreads();   // b2: gates visible

    // ---- E1: scatter-write tanh rows (gB) ----
#pragma unroll
    for (int nt = 0; nt < 5; ++nt) {
      const int c = w * 80 + nt * 16 + ar;
      if (c < HH) {
#pragma unroll
        for (int i = 0; i < 4; ++i) {
          const int r = g * 4 + i;
          if (gB[r]) {
            unsigned short hb = bf16_rne(hnw[nt][i]);
            hh[r][c] = hb;
            hl[r][c] = bf16_rne(hnw[nt][i] - bf16_tof(hb));
          }
        }
      }
    }
    __syncthreads();   // b3: E1 writes visible

    // ---- E2: linear xin/zero updates + coalesced hout/dd ----
#pragma unroll
    for (int r = 0; r < SBR; ++r) {
      if (gDP[r]) {
        if (gX[r]) {
          hh[r][tid] = __builtin_nontemporal_load(&La.xin_h[(xrow + r) * KD + tid]);
          hl[r][tid] = __builtin_nontemporal_load(&La.xin_l[(xrow + r) * KD + tid]);
        } else if (!gB[r] && !gH[r]) {
          hh[r][tid] = 0;
          hl[r][tid] = 0;
        }
      }
      unsigned short hv = hh[r][tid], lv = hl[r][tid];
      if (La.hout_h) {
        __builtin_nontemporal_store(hv, &La.hout_h[(xrow + r) * KD + tid]);
        __builtin_nontemporal_store(lv, &La.hout_l[(xrow + r) * KD + tid]);
      }
      if (La.dd && t == LSEQ - 1)
        __builtin_nontemporal_store(bf16_tof(hv) + bf16_tof(lv), &La.dd[(size_t)(b0 + r) * KD + tid]);
    }
    __syncthreads();   // b4: hh final before next phase A
  }

#pragma unroll
  for (int r = 0; r < SBR; ++r)
    __builtin_nontemporal_store(((unsigned int)hh[r][tid] << 16) | hl[r][tid],
                                &La.hst[(size_t)(b0 + r) * KD + tid]);
  if (tid < SBR) { La.aT[b0 + tid] = sAT[tid]; La.dT[b0 + tid] = sDT[tid]; }
}

// ---------------- host ----------------
extern "C" void kernel_launch(void* const* d_in, const int* in_sizes, int n_in,
                              void* d_out, int out_size, void* d_ws, size_t ws_size,
                              hipStream_t stream)
{
  (void)in_sizes; (void)n_in; (void)out_size;
  const float* x    = (const float*)d_in[0];
  const int*   mask = (const int*)d_in[2];
  const float* Wemb = (const float*)d_in[3];
  const float* bemb = (const float*)d_in[4];
  const float* Wm   = (const float*)d_in[5];
  const float* Um   = (const float*)d_in[6];
  const float* bm   = (const float*)d_in[7];
  const float* Wa1  = (const float*)d_in[8];
  const float* Ua1  = (const float*)d_in[9];
  const float* ba1  = (const float*)d_in[10];
  const float* Wa2  = (const float*)d_in[11];
  const float* ba2  = (const float*)d_in[12];
  float* out = (float*)d_out;

  const size_t FIXED = (size_t)162 << 20;
  const size_t PER_CH = (size_t)12 << 20;
  int CH = 4;
  {
    const int cands[2] = {8, 4};   // prefer small CH: fewer wasted pipeline slots
    for (int i = 0; i < 2; ++i)
      if (FIXED + (size_t)cands[i] * PER_CH <= ws_size) { CH = cands[i]; break; }
  }
  const int NCH = LSEQ / CH;

  char* p = (char*)d_ws;
  auto alloc = [&](size_t bytes) { char* r = p; p += (bytes + 255) & ~(size_t)255; return r; };

  float* Ucat  = (float*)alloc((size_t)KD * NC * 4);
  float* Wcat  = (float*)alloc((size_t)KD * NC * 4);
  float* Wcomb = (float*)alloc((size_t)KD * NC * 4);
  float* bias1 = (float*)alloc(N1 * 4);
  float* bias2 = (float*)alloc(NC * 4);
  unsigned short* BT1h = (unsigned short*)alloc((size_t)N1 * KD * 2);
  unsigned short* BT1l = (unsigned short*)alloc((size_t)N1 * KD * 2);
  unsigned short* BT2h = (unsigned short*)alloc((size_t)NC * KD * 2);
  unsigned short* BT2l = (unsigned short*)alloc((size_t)NC * KD * 2);
  unsigned short* UTh  = (unsigned short*)alloc((size_t)NC * KD * 2);
  unsigned short* UTl  = (unsigned short*)alloc((size_t)NC * KD * 2);
  unsigned short* Upk  = (unsigned short*)alloc((size_t)8 * 80 * 1024 * 2);
  int* acts0 = (int*)alloc((size_t)LSEQ * BSZ * 4);
  int* ndms0 = (int*)alloc((size_t)LSEQ * BSZ * 4);
  int* acts1 = (int*)alloc((size_t)LSEQ * BSZ * 4);
  int* ndms1 = (int*)alloc((size_t)LSEQ * BSZ * 4);
  unsigned int* hst0 = (unsigned int*)alloc((size_t)BSZ * KD * 4);
  unsigned int* hst1 = (unsigned int*)alloc((size_t)BSZ * KD * 4);
  unsigned int* hst2 = (unsigned int*)alloc((size_t)BSZ * KD * 4);
  int* aT0 = (int*)alloc(BSZ * 4); int* dT0 = (int*)alloc(BSZ * 4);
  int* aT1 = (int*)alloc(BSZ * 4); int* dT1 = (int*)alloc(BSZ * 4);
  int* aT2 = (int*)alloc(BSZ * 4); int* dT2 = (int*)alloc(BSZ * 4);
  const size_t XEL = (size_t)BSZ * LSEQ * KD;
  unsigned short* xph = (unsigned short*)alloc(XEL * 2);
  unsigned short* xpl = (unsigned short*)alloc(XEL * 2);
  const size_t CE = (size_t)CH * BSZ * KD;
  unsigned short* xeh = (unsigned short*)alloc(CE * 2);
  unsigned short* xel = (unsigned short*)alloc(CE * 2);
  unsigned short* h0h[3], *h0l[3], *h1h[3], *h1l[3];
  for (int i = 0; i < 3; ++i) {
    h0h[i] = (unsigned short*)alloc(CE * 2); h0l[i] = (unsigned short*)alloc(CE * 2);
    h1h[i] = (unsigned short*)alloc(CE * 2); h1l[i] = (unsigned short*)alloc(CE * 2);
  }
  float* XP0 = (float*)alloc((size_t)CH * BSZ * NC * 4);
  float* XP1 = (float*)alloc((size_t)CH * BSZ * NC * 4);
  float* XP2 = (float*)alloc((size_t)CH * BSZ * NC * 4);

  concat_k<<<(KD * NC + 255) / 256, 256, 0, stream>>>(Um, Ua1, Wm, Wa1, bm, ba1, Ucat, Wcat, bias2);
  comb_k<<<KD, NC, 0, stream>>>(Wemb, Wcat, Wcomb);
  bcomb_k<<<1, NC, 0, stream>>>(bemb, Wcat, bias2, bias1);
  tsplit_k<<<dim3(16, 16), 256, 0, stream>>>(Wemb, HH, BT1h, BT1l, 0);
  tsplit_k<<<dim3(16, 20), 256, 0, stream>>>(Wcomb, NC, BT1h, BT1l, HH);
  tsplit_k<<<dim3(16, 20), 256, 0, stream>>>(Wcat, NC, BT2h, BT2l, 0);
  tsplit_k<<<dim3(16, 20), 256, 0, stream>>>(Ucat, NC, UTh, UTl, 0);
  upack_k<<<(8 * 80 * 2 * 64 + 255) / 256, 256, 0, stream>>>(UTh, UTl, Upk);
  splitx_k<<<(int)((XEL / 4 + 255) / 256), 256, 0, stream>>>(x, xph, xpl, (int)(XEL / 4));

  for (int s = 0; s < NCH + 4; ++s) {
    const int c0i = s, c1i = s - 2, c2i = s - 4;
    const bool a0 = (c0i >= 0 && c0i < NCH);
    const bool a1 = (c1i >= 0 && c1i < NCH);
    const bool a2 = (c2i >= 0 && c2i < NCH);
    const int s0 = a0 ? (c0i % 3) : 0, s1 = a1 ? (c1i % 3) : 0, s2 = a2 ? (c2i % 3) : 0;

    if (a0) gemm_k<1, 1><<<CH * 36, 256, 0, stream>>>(xph, xpl, BT1h, BT1l, bias1, 9, c0i * CH,
                                                      xeh, xel, XP0);
    if (a1) gemm_k<0, 2><<<CH * 20, 256, 0, stream>>>(h0h[s1], h0l[s1], BT2h, BT2l, bias2, 5, 0,
                                                      nullptr, nullptr, XP1);
    if (a2) gemm_k<0, 2><<<CH * 20, 256, 0, stream>>>(h1h[s2], h1l[s2], BT2h, BT2l, bias2, 5, 0,
                                                      nullptr, nullptr, XP2);

    Args3 A3{};
    A3.l[0] = LayerArgs{ xeh, xel, XP0, nullptr, nullptr, acts0, ndms0,
                         h0h[s0], h0l[s0], hst0, aT0, dT0, nullptr,
                         0, c0i * CH, c0i == 0, a0 ? 1 : 0 };
    A3.l[1] = LayerArgs{ h0h[s1], h0l[s1], XP1, acts0, ndms0, acts1, ndms1,
                         h1h[s1], h1l[s1], hst1, aT1, dT1, nullptr,
                         0, c1i * CH, c1i == 0, a1 ? 1 : 0 };
    A3.l[2] = LayerArgs{ h1h[s2], h1l[s2], XP2, acts1, ndms1, nullptr, nullptr,
                         nullptr, nullptr, hst2, aT2, dT2, out,
                         1, c2i * CH, c2i == 0, a2 ? 1 : 0 };
    scan3_k<<<96, 512, 0, stream>>>(A3, Upk, Wa2, ba2, mask, CH);
  }
}

// Round 13
// 5769.238 us; speedup vs baseline: 1.7407x; 1.0202x over previous
//
#include <hip/hip_runtime.h>

#define BSZ 512
#define LSEQ 128
#define HH 512
#define AA 128
#define NC 640    // H + A
#define N1 1152   // H + NC
#define KD 512
#define SBR 16    // batch rows per scan block

typedef short s8v __attribute__((ext_vector_type(8)));
typedef float f4v __attribute__((ext_vector_type(4)));

__device__ __forceinline__ unsigned short bf16_rne(float f) {
  unsigned int u = __float_as_uint(f);
  u += 0x7fffu + ((u >> 16) & 1u);
  return (unsigned short)(u >> 16);
}
__device__ __forceinline__ float bf16_tof(unsigned short s) {
  return __uint_as_float(((unsigned int)s) << 16);
}
__device__ __forceinline__ float fast_tanh(float x) {
  float t = __expf(2.f * x);
  return 1.f - 2.f / (t + 1.f);
}

// ---------------- prep kernels ----------------

__global__ __launch_bounds__(256) void concat_k(
    const float* __restrict__ U, const float* __restrict__ Ua1,
    const float* __restrict__ W, const float* __restrict__ Wa1,
    const float* __restrict__ bb, const float* __restrict__ ba1,
    float* __restrict__ Ucat, float* __restrict__ Wcat, float* __restrict__ bias2)
{
  int idx = blockIdx.x * 256 + threadIdx.x;
  if (idx < KD * NC) {
    int k = idx / NC, c = idx % NC;
    Ucat[idx] = (c < HH) ? U[k * HH + c] : Ua1[k * AA + (c - HH)];
    Wcat[idx] = (c < HH) ? W[k * HH + c] : Wa1[k * AA + (c - HH)];
  }
  if (idx < NC) bias2[idx] = (idx < HH) ? bb[idx] : ba1[idx - HH];
}

__global__ __launch_bounds__(NC) void comb_k(
    const float* __restrict__ Wemb, const float* __restrict__ Wcat,
    float* __restrict__ Wcomb)
{
  __shared__ float arow[KD];
  int m = blockIdx.x, n = threadIdx.x;
  for (int i = threadIdx.x; i < KD; i += NC) arow[i] = Wemb[m * HH + i];
  __syncthreads();
  float a0 = 0.f, a1 = 0.f, a2 = 0.f, a3 = 0.f;
  for (int k = 0; k < KD; k += 4) {
    a0 = fmaf(arow[k],     Wcat[(size_t)(k)     * NC + n], a0);
    a1 = fmaf(arow[k + 1], Wcat[(size_t)(k + 1) * NC + n], a1);
    a2 = fmaf(arow[k + 2], Wcat[(size_t)(k + 2) * NC + n], a2);
    a3 = fmaf(arow[k + 3], Wcat[(size_t)(k + 3) * NC + n], a3);
  }
  Wcomb[(size_t)m * NC + n] = (a0 + a1) + (a2 + a3);
}

__global__ __launch_bounds__(NC) void bcomb_k(
    const float* __restrict__ bemb, const float* __restrict__ Wcat,
    const float* __restrict__ bias2, float* __restrict__ bias1)
{
  __shared__ float be[KD];
  int n = threadIdx.x;
  for (int i = n; i < KD; i += NC) be[i] = bemb[i];
  __syncthreads();
  float acc = 0.f;
  for (int k = 0; k < KD; ++k) acc = fmaf(be[k], Wcat[(size_t)k * NC + n], acc);
  bias1[HH + n] = acc + bias2[n];
  if (n < HH) bias1[n] = bemb[n];
}

// transpose + split f32 [KD][N] -> bf16 hi/lo [N][KD]
__global__ __launch_bounds__(256) void tsplit_k(
    const float* __restrict__ src, int N,
    unsigned short* __restrict__ dsth, unsigned short* __restrict__ dstl, int row_off)
{
  __shared__ float tile[32][33];
  int k0 = blockIdx.x * 32, n0 = blockIdx.y * 32;
  int tx = threadIdx.x & 31, ty = threadIdx.x >> 5;
  for (int i = ty; i < 32; i += 8) {
    int n = n0 + tx;
    tile[i][tx] = (n < N) ? src[(size_t)(k0 + i) * N + n] : 0.f;
  }
  __syncthreads();
  for (int i = ty; i < 32; i += 8) {
    int n = n0 + i;
    if (n >= N) continue;
    float v = tile[tx][i];
    unsigned short h = bf16_rne(v);
    unsigned short l = bf16_rne(v - bf16_tof(h));
    dsth[(size_t)(row_off + n) * KD + k0 + tx] = h;
    dstl[(size_t)(row_off + n) * KD + k0 + tx] = l;
  }
}

// split f32 -> bf16 hi/lo planes (flat)
__global__ __launch_bounds__(256) void splitx_k(
    const float* __restrict__ x, unsigned short* __restrict__ xh,
    unsigned short* __restrict__ xl, int n4)
{
  int i = blockIdx.x * 256 + threadIdx.x;
  if (i >= n4) return;
  const float4 v = *(const float4*)&x[(size_t)i * 4];
  unsigned short h0 = bf16_rne(v.x), h1 = bf16_rne(v.y), h2 = bf16_rne(v.z), h3 = bf16_rne(v.w);
  unsigned short l0 = bf16_rne(v.x - bf16_tof(h0));
  unsigned short l1 = bf16_rne(v.y - bf16_tof(h1));
  unsigned short l2 = bf16_rne(v.z - bf16_tof(h2));
  unsigned short l3 = bf16_rne(v.w - bf16_tof(h3));
  *(ushort4*)&xh[(size_t)i * 4] = make_ushort4(h0, h1, h2, h3);
  *(ushort4*)&xl[(size_t)i * 4] = make_ushort4(l0, l1, l2, l3);
}

// pack UT hi/lo into per-wave, consumption-ordered contiguous tiles
__global__ __launch_bounds__(256) void upack_k(
    const unsigned short* __restrict__ UTh, const unsigned short* __restrict__ UTl,
    unsigned short* __restrict__ pk)
{
  int gid = blockIdx.x * 256 + threadIdx.x;   // tile*128 + p*64 + lane
  if (gid >= 8 * 80 * 2 * 64) return;
  int lane = gid & 63;
  int p = (gid >> 6) & 1;
  int tile = gid >> 7;                        // w*80 + ks*5 + nt
  int w = tile / 80;
  int rem = tile - w * 80;
  int ks = rem / 5, nt = rem - ks * 5;
  const unsigned short* src = p ? UTl : UTh;
  size_t soff = (size_t)(w * 80 + nt * 16 + (lane & 15)) * KD + ks * 32 + (lane >> 4) * 8;
  *(s8v*)&pk[(size_t)gid * 8] = *(const s8v*)&src[soff];
}

// ---------------- split-bf16 3-term MFMA GEMM ----------------
template<int REMAP, int OMODE>
__global__ __launch_bounds__(256, 2) void gemm_k(
    const unsigned short* __restrict__ Ah, const unsigned short* __restrict__ Al,
    const unsigned short* __restrict__ BTh, const unsigned short* __restrict__ BTl,
    const float* __restrict__ bias, int NT, int c0,
    unsigned short* __restrict__ o_xeh, unsigned short* __restrict__ o_xel,
    float* __restrict__ o_xp)
{
  __shared__ __align__(16) unsigned short As_h[128][72];
  __shared__ __align__(16) unsigned short As_l[128][72];
  __shared__ __align__(16) unsigned short Bs_h[128][72];
  __shared__ __align__(16) unsigned short Bs_l[128][72];
  const int tid = threadIdx.x;
  const int lane = tid & 63, w = tid >> 6;
  const int wm = w >> 1, wn = w & 1;
  const int m0 = (blockIdx.x / NT) * 128, n0 = (blockIdx.x % NT) * 128;

  f4v acc[4][4];
#pragma unroll
  for (int i = 0; i < 4; ++i)
#pragma unroll
    for (int j = 0; j < 4; ++j) acc[i][j] = (f4v){0.f, 0.f, 0.f, 0.f};

  for (int kt = 0; kt < KD; kt += 64) {
    __syncthreads();
#pragma unroll
    for (int p = 0; p < 4; ++p) {
      int li = tid + p * 256;
      int row = li >> 3, kc = (li & 7) << 3;
      int m = m0 + row;
      int arow = REMAP ? ((m & 511) * 128 + c0 + (m >> 9)) : m;
      *(s8v*)&As_h[row][kc] = *(const s8v*)&Ah[(size_t)arow * KD + kt + kc];
      *(s8v*)&As_l[row][kc] = *(const s8v*)&Al[(size_t)arow * KD + kt + kc];
      *(s8v*)&Bs_h[row][kc] = *(const s8v*)&BTh[(size_t)(n0 + row) * KD + kt + kc];
      *(s8v*)&Bs_l[row][kc] = *(const s8v*)&BTl[(size_t)(n0 + row) * KD + kt + kc];
    }
    __syncthreads();
#pragma unroll
    for (int kk = 0; kk < 2; ++kk) {
      const int kb = kk * 32 + (lane >> 4) * 8;
      s8v ah[4], alo[4], bh[4], blo[4];
#pragma unroll
      for (int i = 0; i < 4; ++i) {
        int ra = wm * 64 + i * 16 + (lane & 15);
        int rb = wn * 64 + i * 16 + (lane & 15);
        ah[i]  = *(const s8v*)&As_h[ra][kb];
        alo[i] = *(const s8v*)&As_l[ra][kb];
        bh[i]  = *(const s8v*)&Bs_h[rb][kb];
        blo[i] = *(const s8v*)&Bs_l[rb][kb];
      }
#pragma unroll
      for (int mi = 0; mi < 4; ++mi)
#pragma unroll
        for (int ni = 0; ni < 4; ++ni) {
          acc[mi][ni] = __builtin_amdgcn_mfma_f32_16x16x32_bf16(alo[mi], bh[ni], acc[mi][ni], 0, 0, 0);
          acc[mi][ni] = __builtin_amdgcn_mfma_f32_16x16x32_bf16(ah[mi], blo[ni], acc[mi][ni], 0, 0, 0);
          acc[mi][ni] = __builtin_amdgcn_mfma_f32_16x16x32_bf16(ah[mi], bh[ni], acc[mi][ni], 0, 0, 0);
        }
    }
  }
#pragma unroll
  for (int mi = 0; mi < 4; ++mi) {
#pragma unroll
    for (int ni = 0; ni < 4; ++ni) {
      int n = n0 + wn * 64 + ni * 16 + (lane & 15);
      float bv = bias[n];
#pragma unroll
      for (int r = 0; r < 4; ++r) {
        int m = m0 + wm * 64 + mi * 16 + (lane >> 4) * 4 + r;
        float val = acc[mi][ni][r] + bv;
        if (OMODE == 1) {
          if (n < HH) {
            unsigned short hb = bf16_rne(val);
            unsigned short lb = bf16_rne(val - bf16_tof(hb));
            __builtin_nontemporal_store(hb, &o_xeh[(size_t)m * KD + n]);
            __builtin_nontemporal_store(lb, &o_xel[(size_t)m * KD + n]);
          } else {
            __builtin_nontemporal_store(val, &o_xp[(size_t)m * NC + (n - HH)]);
          }
        } else {
          __builtin_nontemporal_store(val, &o_xp[(size_t)m * NC + n]);
        }
      }
    }
  }
}

// ---------------- fused 3-layer MFMA scan ----------------
struct LayerArgs {
  const unsigned short* xin_h; const unsigned short* xin_l;
  const float* xp;
  const int* ain; const int* nin;
  int* aout; int* nout;
  unsigned short* hout_h; unsigned short* hout_l;
  unsigned int* hst;
  int* aT; int* dT;
  float* dd;
  int LL, c0, FIRST, active;
};
struct Args3 { LayerArgs l[3]; };

// 96 blocks x 512 threads; block b: layer = b>>5, rowblock = b&31 (16 rows).
// Phase A: 7-slot LDS ring (depth-6 pipeline, vmcnt(12)); Y stays in regs.
// Scan STORES are temporal (fast L2 drain — keeps them out of the counted
// vmcnt chain); streaming LOADS stay NT to protect weight L2 residency.
__global__ __launch_bounds__(512) void scan3_k(
    Args3 A3,
    const unsigned short* __restrict__ Upk,
    const float* __restrict__ Wa2, const float* __restrict__ ba2,
    const int* __restrict__ mask, int CH)
{
  const int lay = blockIdx.x >> 5;
  const LayerArgs La = A3.l[lay];
  if (!La.active) return;

  __shared__ __align__(16) unsigned short hh[SBR][520];
  __shared__ __align__(16) unsigned short hl[SBR][520];
  __shared__ __align__(16) unsigned short ring[8][7][2][512]; // 112 KB
  __shared__ float lgp[2][SBR][2];
  __shared__ float sWa2[AA * 2];
  __shared__ float sba2[2];
  __shared__ int gB[SBR], gH[SBR], gX[SBR], gDP[SBR], sAT[SBR], sDT[SBR];

  const int tid = threadIdx.x;
  const int lane = tid & 63, w = tid >> 6;
  const int b0 = (blockIdx.x & 31) * SBR;
  const int ar = lane & 15, g = lane >> 4;

  if (tid < AA * 2) sWa2[tid] = Wa2[tid];
  if (tid < 2) sba2[tid] = ba2[tid];
  if (tid < SBR) {
    sAT[tid] = La.FIRST ? 0 : La.aT[b0 + tid];
    sDT[tid] = La.FIRST ? 0 : La.dT[b0 + tid];
  }
#pragma unroll
  for (int r = 0; r < SBR; ++r) {
    unsigned int u = La.FIRST ? 0u : __builtin_nontemporal_load(&La.hst[(size_t)(b0 + r) * KD + tid]);
    hh[r][tid] = (unsigned short)(u >> 16);
    hl[r][tid] = (unsigned short)(u & 0xffff);
  }
  __syncthreads();

  const unsigned short* __restrict__ wbase = Upk + (size_t)w * 80 * 1024 + (size_t)lane * 8;

  auto stage = [&](int atile, int slot) {
    const unsigned short* gh = wbase + (size_t)atile * 1024;
    __builtin_amdgcn_global_load_lds(
        (const __attribute__((address_space(1))) void*)gh,
        (__attribute__((address_space(3))) void*)&ring[w][slot][0][0], 16, 0, 0);
    __builtin_amdgcn_global_load_lds(
        (const __attribute__((address_space(1))) void*)(gh + 512),
        (__attribute__((address_space(3))) void*)&ring[w][slot][1][0], 16, 0, 0);
  };

  // ring state: consume slot cs (tile J), produce slot ps = (J+6)%7, addr wt = (J+6)%80
  int wt = 6, ps = 6, cs = 0;
#pragma unroll
  for (int j = 0; j < 6; ++j) stage(j, j);

  for (int tl = 0; tl < CH; ++tl) {
    const int t = La.c0 + tl;
    const size_t xrow = (size_t)tl * BSZ + b0;

    // gate inputs (tid<16), hidden under phase A
    int pA0 = 0, pDP = 0, pmt = 0, pmn = 0;
    if (tid < SBR) {
      int b = b0 + tid;
      pA0 = (La.ain && t < LSEQ - 1) ? La.ain[(t + 1) * BSZ + b] : 0;
      pDP = La.nin ? La.nin[t * BSZ + b] : mask[b * LSEQ + t];
      pmt = mask[b * LSEQ + t];
      pmn = (t < LSEQ - 1) ? mask[b * LSEQ + t + 1] : 0;
    }

    // ---- phase A: Y = h @ Ucat (Y stays in regs) ----
    f4v acc[5];
#pragma unroll
    for (int nt = 0; nt < 5; ++nt) acc[nt] = (f4v){0.f, 0.f, 0.f, 0.f};

    for (int ks = 0; ks < 16; ++ks) {
      const int ko = ks * 32 + g * 8;
      s8v ah = *(const s8v*)&hh[ar][ko];
      s8v al = *(const s8v*)&hl[ar][ko];
#pragma unroll
      for (int nt = 0; nt < 5; ++nt) {
        stage(wt, ps);
        wt = (wt == 79) ? 0 : wt + 1;
        ps = (ps == 6) ? 0 : ps + 1;
        asm volatile("s_waitcnt vmcnt(12)" ::: "memory");
        s8v bh = *(const s8v*)&ring[w][cs][0][lane * 8];
        s8v bl = *(const s8v*)&ring[w][cs][1][lane * 8];
        cs = (cs == 6) ? 0 : cs + 1;
        acc[nt] = __builtin_amdgcn_mfma_f32_16x16x32_bf16(al, bh, acc[nt], 0, 0, 0);
        acc[nt] = __builtin_amdgcn_mfma_f32_16x16x32_bf16(ah, bl, acc[nt], 0, 0, 0);
        acc[nt] = __builtin_amdgcn_mfma_f32_16x16x32_bf16(ah, bh, acc[nt], 0, 0, 0);
      }
    }

    // ---- phase B: producer-ownership tanh / pol+partial-logits ----
    float hnw[5][4];
    float sj[8];
#pragma unroll
    for (int v = 0; v < 8; ++v) sj[v] = 0.f;
#pragma unroll
    for (int nt = 0; nt < 5; ++nt) {
      const int c = w * 80 + nt * 16 + ar;
      if (c < HH) {
#pragma unroll
        for (int i = 0; i < 4; ++i) {
          float xv = __builtin_nontemporal_load(&La.xp[(xrow + g * 4 + i) * NC + c]);
          hnw[nt][i] = fast_tanh(xv + acc[nt][i]);
        }
      } else {
        const int a = c - HH;
        const float w0 = sWa2[a * 2], w1 = sWa2[a * 2 + 1];
#pragma unroll
        for (int i = 0; i < 4; ++i) {
          float xv = __builtin_nontemporal_load(&La.xp[(xrow + g * 4 + i) * NC + c]);
          float pv = fmaxf(xv + acc[nt][i], 0.f);
          sj[i * 2]     = fmaf(pv, w0, sj[i * 2]);
          sj[i * 2 + 1] = fmaf(pv, w1, sj[i * 2 + 1]);
        }
      }
    }
    if (w >= 6) {
#pragma unroll
      for (int v = 0; v < 8; ++v) {
        sj[v] += __shfl_xor(sj[v], 1);
        sj[v] += __shfl_xor(sj[v], 2);
        sj[v] += __shfl_xor(sj[v], 4);
        sj[v] += __shfl_xor(sj[v], 8);
      }
      if (ar == 0) {
#pragma unroll
        for (int i = 0; i < 4; ++i) {
          lgp[w - 6][g * 4 + i][0] = sj[i * 2];
          lgp[w - 6][g * 4 + i][1] = sj[i * 2 + 1];
        }
      }
    }
    __syncthreads();   // b1: lgp visible

    // ---- gates (tid<16) ----
    if (tid < SBR) {
      float l0 = lgp[0][tid][0] + lgp[1][tid][0] + sba2[0];
      float l1 = lgp[0][tid][1] + lgp[1][tid][1] + sba2[1];
      int E = pmt * (1 - pmn);
      int act = (l0 >= l1) ? 1 : 0;
      if (pA0 > 0) act = 1;
      if (La.LL) act = 1;
      if (E > 0) act = 0;
      int DT = sDT[tid];
      int both  = (1 - pA0) * pDP * act * DT;
      int honly = DT * act * (pA0 + (1 - pA0) * (1 - pDP));
      int xonly = pDP * (1 - pA0) * (1 - act + act * (1 - DT));
      int ndm = pDP * (both + xonly + honly);
      int aout = pDP ? act : sAT[tid];
      gB[tid] = both; gH[tid] = honly; gX[tid] = xonly; gDP[tid] = pDP;
      sAT[tid] = aout; sDT[tid] = ndm;
      if (La.aout) La.aout[t * BSZ + b0 + tid] = aout;
      if (La.nout) La.nout[t * BSZ + b0 + tid] = ndm;
    }
    __syncthreads();   // b2: gates visible

    // ---- E1: scatter-write tanh rows (gB) ----
#pragma unroll
    for (int nt = 0; nt < 5; ++nt) {
      const int c = w * 80 + nt * 16 + ar;
      if (c < HH) {
#pragma unroll
        for (int i = 0; i < 4; ++i) {
          const int r = g * 4 + i;
          if (gB[r]) {
            unsigned short hb = bf16_rne(hnw[nt][i]);
            hh[r][c] = hb;
            hl[r][c] = bf16_rne(hnw[nt][i] - bf16_tof(hb));
          }
        }
      }
    }
    __syncthreads();   // b3: E1 writes visible

    // ---- E2: linear xin/zero updates + coalesced hout/dd (temporal stores) ----
#pragma unroll
    for (int r = 0; r < SBR; ++r) {
      if (gDP[r]) {
        if (gX[r]) {
          hh[r][tid] = __builtin_nontemporal_load(&La.xin_h[(xrow + r) * KD + tid]);
          hl[r][tid] = __builtin_nontemporal_load(&La.xin_l[(xrow + r) * KD + tid]);
        } else if (!gB[r] && !gH[r]) {
          hh[r][tid] = 0;
          hl[r][tid] = 0;
        }
      }
      unsigned short hv = hh[r][tid], lv = hl[r][tid];
      if (La.hout_h) {
        La.hout_h[(xrow + r) * KD + tid] = hv;
        La.hout_l[(xrow + r) * KD + tid] = lv;
      }
      if (La.dd && t == LSEQ - 1)
        La.dd[(size_t)(b0 + r) * KD + tid] = bf16_tof(hv) + bf16_tof(lv);
    }
    __syncthreads();   // b4: hh final before next phase A
  }

#pragma unroll
  for (int r = 0; r < SBR; ++r)
    La.hst[(size_t)(b0 + r) * KD + tid] = ((unsigned int)hh[r][tid] << 16) | hl[r][tid];
  if (tid < SBR) { La.aT[b0 + tid] = sAT[tid]; La.dT[b0 + tid] = sDT[tid]; }
}

// ---------------- host ----------------
extern "C" void kernel_launch(void* const* d_in, const int* in_sizes, int n_in,
                              void* d_out, int out_size, void* d_ws, size_t ws_size,
                              hipStream_t stream)
{
  (void)in_sizes; (void)n_in; (void)out_size;
  const float* x    = (const float*)d_in[0];
  const int*   mask = (const int*)d_in[2];
  const float* Wemb = (const float*)d_in[3];
  const float* bemb = (const float*)d_in[4];
  const float* Wm   = (const float*)d_in[5];
  const float* Um   = (const float*)d_in[6];
  const float* bm   = (const float*)d_in[7];
  const float* Wa1  = (const float*)d_in[8];
  const float* Ua1  = (const float*)d_in[9];
  const float* ba1  = (const float*)d_in[10];
  const float* Wa2  = (const float*)d_in[11];
  const float* ba2  = (const float*)d_in[12];
  float* out = (float*)d_out;

  const size_t FIXED = (size_t)162 << 20;
  const size_t PER_CH = (size_t)12 << 20;
  int CH = 4;
  {
    const int cands[2] = {8, 4};
    for (int i = 0; i < 2; ++i)
      if (FIXED + (size_t)cands[i] * PER_CH <= ws_size) { CH = cands[i]; break; }
  }
  const int NCH = LSEQ / CH;

  char* p = (char*)d_ws;
  auto alloc = [&](size_t bytes) { char* r = p; p += (bytes + 255) & ~(size_t)255; return r; };

  float* Ucat  = (float*)alloc((size_t)KD * NC * 4);
  float* Wcat  = (float*)alloc((size_t)KD * NC * 4);
  float* Wcomb = (float*)alloc((size_t)KD * NC * 4);
  float* bias1 = (float*)alloc(N1 * 4);
  float* bias2 = (float*)alloc(NC * 4);
  unsigned short* BT1h = (unsigned short*)alloc((size_t)N1 * KD * 2);
  unsigned short* BT1l = (unsigned short*)alloc((size_t)N1 * KD * 2);
  unsigned short* BT2h = (unsigned short*)alloc((size_t)NC * KD * 2);
  unsigned short* BT2l = (unsigned short*)alloc((size_t)NC * KD * 2);
  unsigned short* UTh  = (unsigned short*)alloc((size_t)NC * KD * 2);
  unsigned short* UTl  = (unsigned short*)alloc((size_t)NC * KD * 2);
  unsigned short* Upk  = (unsigned short*)alloc((size_t)8 * 80 * 1024 * 2);
  int* acts0 = (int*)alloc((size_t)LSEQ * BSZ * 4);
  int* ndms0 = (int*)alloc((size_t)LSEQ * BSZ * 4);
  int* acts1 = (int*)alloc((size_t)LSEQ * BSZ * 4);
  int* ndms1 = (int*)alloc((size_t)LSEQ * BSZ * 4);
  unsigned int* hst0 = (unsigned int*)alloc((size_t)BSZ * KD * 4);
  unsigned int* hst1 = (unsigned int*)alloc((size_t)BSZ * KD * 4);
  unsigned int* hst2 = (unsigned int*)alloc((size_t)BSZ * KD * 4);
  int* aT0 = (int*)alloc(BSZ * 4); int* dT0 = (int*)alloc(BSZ * 4);
  int* aT1 = (int*)alloc(BSZ * 4); int* dT1 = (int*)alloc(BSZ * 4);
  int* aT2 = (int*)alloc(BSZ * 4); int* dT2 = (int*)alloc(BSZ * 4);
  const size_t XEL = (size_t)BSZ * LSEQ * KD;
  unsigned short* xph = (unsigned short*)alloc(XEL * 2);
  unsigned short* xpl = (unsigned short*)alloc(XEL * 2);
  const size_t CE = (size_t)CH * BSZ * KD;
  unsigned short* xeh = (unsigned short*)alloc(CE * 2);
  unsigned short* xel = (unsigned short*)alloc(CE * 2);
  unsigned short* h0h[3], *h0l[3], *h1h[3], *h1l[3];
  for (int i = 0; i < 3; ++i) {
    h0h[i] = (unsigned short*)alloc(CE * 2); h0l[i] = (unsigned short*)alloc(CE * 2);
    h1h[i] = (unsigned short*)alloc(CE * 2); h1l[i] = (unsigned short*)alloc(CE * 2);
  }
  float* XP0 = (float*)alloc((size_t)CH * BSZ * NC * 4);
  float* XP1 = (float*)alloc((size_t)CH * BSZ * NC * 4);
  float* XP2 = (float*)alloc((size_t)CH * BSZ * NC * 4);

  concat_k<<<(KD * NC + 255) / 256, 256, 0, stream>>>(Um, Ua1, Wm, Wa1, bm, ba1, Ucat, Wcat, bias2);
  comb_k<<<KD, NC, 0, stream>>>(Wemb, Wcat, Wcomb);
  bcomb_k<<<1, NC, 0, stream>>>(bemb, Wcat, bias2, bias1);
  tsplit_k<<<dim3(16, 16), 256, 0, stream>>>(Wemb, HH, BT1h, BT1l, 0);
  tsplit_k<<<dim3(16, 20), 256, 0, stream>>>(Wcomb, NC, BT1h, BT1l, HH);
  tsplit_k<<<dim3(16, 20), 256, 0, stream>>>(Wcat, NC, BT2h, BT2l, 0);
  tsplit_k<<<dim3(16, 20), 256, 0, stream>>>(Ucat, NC, UTh, UTl, 0);
  upack_k<<<(8 * 80 * 2 * 64 + 255) / 256, 256, 0, stream>>>(UTh, UTl, Upk);
  splitx_k<<<(int)((XEL / 4 + 255) / 256), 256, 0, stream>>>(x, xph, xpl, (int)(XEL / 4));

  for (int s = 0; s < NCH + 4; ++s) {
    const int c0i = s, c1i = s - 2, c2i = s - 4;
    const bool a0 = (c0i >= 0 && c0i < NCH);
    const bool a1 = (c1i >= 0 && c1i < NCH);
    const bool a2 = (c2i >= 0 && c2i < NCH);
    const int s0 = a0 ? (c0i % 3) : 0, s1 = a1 ? (c1i % 3) : 0, s2 = a2 ? (c2i % 3) : 0;

    if (a0) gemm_k<1, 1><<<CH * 36, 256, 0, stream>>>(xph, xpl, BT1h, BT1l, bias1, 9, c0i * CH,
                                                      xeh, xel, XP0);
    if (a1) gemm_k<0, 2><<<CH * 20, 256, 0, stream>>>(h0h[s1], h0l[s1], BT2h, BT2l, bias2, 5, 0,
                                                      nullptr, nullptr, XP1);
    if (a2) gemm_k<0, 2><<<CH * 20, 256, 0, stream>>>(h1h[s2], h1l[s2], BT2h, BT2l, bias2, 5, 0,
                                                      nullptr, nullptr, XP2);

    Args3 A3{};
    A3.l[0] = LayerArgs{ xeh, xel, XP0, nullptr, nullptr, acts0, ndms0,
                         h0h[s0], h0l[s0], hst0, aT0, dT0, nullptr,
                         0, c0i * CH, c0i == 0, a0 ? 1 : 0 };
    A3.l[1] = LayerArgs{ h0h[s1], h0l[s1], XP1, acts0, ndms0, acts1, ndms1,
                         h1h[s1], h1l[s1], hst1, aT1, dT1, nullptr,
                         0, c1i * CH, c1i == 0, a1 ? 1 : 0 };
    A3.l[2] = LayerArgs{ h1h[s2], h1l[s2], XP2, acts1, ndms1, nullptr, nullptr,
                         nullptr, nullptr, hst2, aT2, dT2, out,
                         1, c2i * CH, c2i == 0, a2 ? 1 : 0 };
    scan3_k<<<96, 512, 0, stream>>>(A3, Upk, Wa2, ba2, mask, CH);
  }
}